// Round 2
// baseline (5122.617 us; speedup 1.0000x reference)
//
#include <hip/hip_runtime.h>
#include <math.h>

#define PI_D 3.14159265358979323846
#define TPB 256
typedef unsigned short ushortT;
typedef unsigned int uintT;

__device__ __forceinline__ float2 cxmul(float2 a, float2 b){
  return make_float2(a.x*b.x - a.y*b.y, a.x*b.y + a.y*b.x);
}
__device__ __forceinline__ float bf2f(ushortT u){
  uintT x = ((uintT)u) << 16;
  return __uint_as_float(x);
}
__device__ __forceinline__ ushortT f2bf(float f){
  uintT x = __float_as_uint(f);
  x = x + 0x7FFFu + ((x >> 16) & 1u);
  return (ushortT)(x >> 16);
}

// ---------------- tables ----------------
__global__ void k_tables(double* lf, double* qw){
  if (threadIdx.x == 0){
    lf[0] = 0.0;
    for (int i = 1; i <= 64; ++i) lf[i] = lf[i-1] + log((double)i);
  }
  int j = threadIdx.x;
  if (j < 64){
    double s1 = sin(PI_D*(2*j+1)/128.0);
    double inner = 0.0;
    for (int k = 0; k < 32; ++k)
      inner += (1.0/(double)(2*k+1)) * sin((double)(2*j+1)*(double)(2*k+1)*PI_D/128.0);
    qw[j] = (2.0/32.0) * s1 * inner;
  }
}

__device__ double wigd(const double* lfs, int l, int mp, int m, double lc, double ls){
  if (mp < -l || mp > l || m < -l || m > l) return 0.0;
  int k0 = (m - mp > 0) ? (m - mp) : 0;
  int k1 = (l + m < l - mp) ? (l + m) : (l - mp);
  double base = 0.5*(lfs[l+mp] + lfs[l-mp] + lfs[l+m] + lfs[l-m]);
  double val = 0.0;
  for (int k = k0; k <= k1; ++k){
    double t = base - lfs[l+m-k] - lfs[k] - lfs[mp-m+k] - lfs[l-mp-k]
             + (double)(2*l + m - mp - 2*k)*lc + (double)(mp - m + 2*k)*ls;
    double e = exp(t);
    val += ((mp - m + k) & 1) ? -e : e;
  }
  return val;
}

// Dz[z][l][mi'][n]: d^l_{mi', n-31}(beta_z) for mi' in 0..31 (m' >= 0), n full 0..62
// Deq[l][r][c]: d^l_{r-31, c-31}(pi/2) full
__global__ __launch_bounds__(TPB) void k_wigner(const double* __restrict__ lf,
                                                float* __restrict__ Dz, float* __restrict__ Deq){
  __shared__ double lfs[65];
  if (threadIdx.x < 65) lfs[threadIdx.x] = lf[threadIdx.x];
  __syncthreads();
  int zs = blockIdx.x, l = blockIdx.y;
  double beta = (zs < 64) ? ((double)zs + 0.5)*PI_D/64.0 : PI_D*0.5;
  double ch = cos(beta*0.5), sh = sin(beta*0.5);
  double lc = log(ch), ls = log(sh);
  if (zs < 64){
    for (int idx = threadIdx.x; idx < 2016; idx += TPB){
      int mi = idx/63, c = idx%63;
      Dz[((size_t)(zs*32 + l)*32 + mi)*63 + c] = (float)wigd(lfs, l, mi, c-31, lc, ls);
    }
  } else {
    for (int idx = threadIdx.x; idx < 3969; idx += TPB){
      int r = idx/63, c = idx%63;
      Deq[((size_t)l*63 + r)*63 + c] = (float)wigd(lfs, l, r-31, c-31, lc, ls);
    }
  }
}

// Kh[n][o][i] = scale * sum_p K[i,o,p] * exp(-i*2pi*p*(n-31)/64)
__global__ void k_kh(const float* __restrict__ K, float2* __restrict__ Kh, int I, int O, float scale){
  int idx = blockIdx.x*blockDim.x + threadIdx.x;
  int total = I*O*63;
  if (idx >= total) return;
  int i = idx % I, o = (idx / I) % O, n = idx / (I*O);
  float sr = 0.f, si = 0.f;
  for (int p = 0; p < 64; ++p){
    int t = (p * (n - 31)) & 63;
    float s, c;
    sincosf(-(float)PI_D/32.f * (float)t, &s, &c);
    float kv = K[(i*O + o)*64 + p];
    sr += kv * c; si += kv * s;
  }
  Kh[((size_t)n*O + o)*I + i] = make_float2(sr*scale, si*scale);
}

// ---------------- S2 front ----------------
__global__ void k_s2_fft(const float* __restrict__ x, float2* __restrict__ XH2){
  int idx = blockIdx.x*blockDim.x + threadIdx.x;
  if (idx >= 2*3*64*63) return;
  int mi = idx % 63; int z = (idx/63) & 63; int bc = idx / (63*64);
  int f = (mi + 33) & 63;
  const float* row = x + ((size_t)bc*64 + z)*64;
  float sr = 0.f, si = 0.f;
  for (int a = 0; a < 64; ++a){
    int t = (f*a) & 63;
    float s, c;
    sincosf(-(float)PI_D/32.f * (float)t, &s, &c);
    sr += row[a]*c; si += row[a]*s;
  }
  XH2[idx] = make_float2(sr, si);
}

// F2[bc][l][r] = sum_z qw[z]*d^l_{r-31,0}(beta_z)*XH2[bc][z][r], r full 63
__global__ void k_s2_F(const float* __restrict__ Dz, const double* __restrict__ qw,
                       const float2* __restrict__ XH2, float2* __restrict__ F2){
  int idx = blockIdx.x*blockDim.x + threadIdx.x;
  if (idx >= 2*3*32*63) return;
  int r = idx % 63; int l = (idx/63) & 31; int bc = idx / (63*32);
  float2 acc = make_float2(0,0);
  for (int z = 0; z < 64; ++z){
    float d;
    if (r >= 31) d = Dz[((size_t)(z*32 + l)*32 + (r-31))*63 + 31];
    else {
      d = Dz[((size_t)(z*32 + l)*32 + (31-r))*63 + 31];
      if ((31-r) & 1) d = -d;
    }
    float wv = (float)qw[z] * d;
    float2 v = XH2[((size_t)bc*64 + z)*63 + r];
    acc.x += wv*v.x; acc.y += wv*v.y;
  }
  F2[idx] = acc;
}

// Z[b,o,l,mi',n] = sum_i F2[b,i,l,mi'+31]*Kh[n,o,i]*Deq[l][n][31]   (reduced m)
__global__ void k_s2_zhat(const float* __restrict__ Deq, const float2* __restrict__ F2,
                          const float2* __restrict__ Kh, float2* __restrict__ Z){
  int idx = blockIdx.x*blockDim.x + threadIdx.x;
  if (idx >= 2*25*32*2016) return;
  int n = idx % 63; int mi = (idx/63) & 31; int l = (idx/2016) & 31;
  int o = (idx/(2016*32)) % 25; int b = idx/(2016*32*25);
  float deq0 = Deq[((size_t)l*63 + n)*63 + 31];
  float2 acc = make_float2(0,0);
  for (int i = 0; i < 3; ++i){
    float2 f = F2[((size_t)(b*3 + i)*32 + l)*63 + (mi+31)];
    float2 kh = Kh[((size_t)n*25 + o)*3 + i];
    float2 p = cxmul(f, kh);
    acc.x += p.x; acc.y += p.y;
  }
  Z[((size_t)((b*25+o)*32) + l)*2016 + mi*63 + n] = make_float2(acc.x*deq0, acc.y*deq0);
}

// ---------------- BN stats over bf16 X buffers (25ch each) ----------------
__global__ __launch_bounds__(TPB) void k_bnstats(const ushortT* __restrict__ src, int slotBase,
                                                 double* __restrict__ part){
  int c = blockIdx.x, blk = blockIdx.y;
  const uint2* s4 = (const uint2*)src;
  double s = 0.0, q = 0.0;
  for (int k = 0; k < 8; ++k){
    int g4 = blk*2048 + k*256 + threadIdx.x;   // group of 4 elems; 131072 groups per channel
    int b = g4 >> 16, pos4 = g4 & 65535;
    uint2 u = s4[((size_t)(b*25 + c))*65536 + pos4];
    float v0 = bf2f((ushortT)(u.x & 0xffff)), v1 = bf2f((ushortT)(u.x >> 16));
    float v2 = bf2f((ushortT)(u.y & 0xffff)), v3 = bf2f((ushortT)(u.y >> 16));
    s += (double)v0 + v1 + v2 + v3;
    q += (double)v0*v0 + (double)v1*v1 + (double)v2*v2 + (double)v3*v3;
  }
  __shared__ double sh[TPB], sh2[TPB];
  sh[threadIdx.x] = s; sh2[threadIdx.x] = q;
  __syncthreads();
  for (int o = 128; o > 0; o >>= 1){
    if (threadIdx.x < o){ sh[threadIdx.x] += sh[threadIdx.x+o]; sh2[threadIdx.x] += sh2[threadIdx.x+o]; }
    __syncthreads();
  }
  if (threadIdx.x == 0){
    part[((size_t)(slotBase + c)*64 + blk)*2 + 0] = sh[0];
    part[((size_t)(slotBase + c)*64 + blk)*2 + 1] = sh2[0];
  }
}

__global__ void k_bnfinal(const double* __restrict__ part, const float* __restrict__ g,
                          const float* __restrict__ b, float2* __restrict__ ss, int C){
  int c = blockIdx.x*blockDim.x + threadIdx.x;
  if (c >= C) return;
  double s = 0.0, q = 0.0;
  for (int k = 0; k < 64; ++k){
    s += part[((size_t)c*64 + k)*2 + 0];
    q += part[((size_t)c*64 + k)*2 + 1];
  }
  double N = 524288.0;
  double mu = s / N;
  double var = q / N - mu*mu;
  double sc = (double)g[c] / sqrt(var + 1e-5);
  ss[c] = make_float2((float)sc, (float)((double)b[c] - mu*sc));
}

// ---------------- in-place 64-pt DFT on LDS plane (stride 65) ----------------
template<bool COL>
__device__ void dft64ip(const float2* __restrict__ W, float2* buf){
  const int line = threadIdx.x >> 2;
  const int q = threadIdx.x & 3;
  float2 Bv[2][8];
  #pragma unroll
  for (int kk = 0; kk < 2; ++kk){
    const int k0 = q + 4*kk;
    #pragma unroll
    for (int n0 = 0; n0 < 8; ++n0){
      float2 a = make_float2(0,0);
      #pragma unroll
      for (int n1 = 0; n1 < 8; ++n1){
        const int src = 8*n1 + n0;
        float2 v = COL ? buf[src*65 + line] : buf[line*65 + src];
        float2 wv = W[((n1*k0) & 7) * 8];
        a.x += v.x*wv.x - v.y*wv.y;
        a.y += v.x*wv.y + v.y*wv.x;
      }
      Bv[kk][n0] = cxmul(a, W[(n0*k0) & 63]);
    }
  }
  __syncthreads();
  #pragma unroll
  for (int kk = 0; kk < 2; ++kk){
    const int k0 = q + 4*kk;
    #pragma unroll
    for (int k1 = 0; k1 < 8; ++k1){
      float2 X = make_float2(0,0);
      #pragma unroll
      for (int n0 = 0; n0 < 8; ++n0){
        float2 wv = W[((n0*k1) & 7) * 8];
        X.x += Bv[kk][n0].x*wv.x - Bv[kk][n0].y*wv.y;
        X.y += Bv[kk][n0].x*wv.y + Bv[kk][n0].y*wv.x;
      }
      const int dst = 8*k1 + k0;
      if (COL) buf[dst*65 + line] = X; else buf[line*65 + dst] = X;
    }
  }
}

// ---------------- fused BN+ReLU + fft2 + reduced centered extraction ----------------
__global__ __launch_bounds__(TPB) void k_fft2_fwd(const ushortT* __restrict__ X1, const ushortT* __restrict__ X2,
                                                  const ushortT* __restrict__ X3, const float2* __restrict__ ss,
                                                  float2* __restrict__ XH, int Cin, int z0){
  __shared__ float2 W[64];
  __shared__ __attribute__((aligned(16))) float2 buf[64*65];
  int bc = blockIdx.x, zz = blockIdx.y, z = z0 + zz;
  int b = bc / Cin, ci = bc % Cin;
  const ushortT* src; int cl;
  if (ci < 25){ src = X1; cl = ci; }
  else if (ci < 50){ src = X2; cl = ci - 25; }
  else { src = X3; cl = ci - 50; }
  src += ((size_t)(b*25 + cl)*64 + z)*4096;
  float2 sc = ss[ci];
  if (threadIdx.x < 64){
    double ang = -2.0*PI_D*(double)threadIdx.x/64.0;
    W[threadIdx.x] = make_float2((float)cos(ang), (float)sin(ang));
  }
  const uintT* s32 = (const uintT*)src;
  for (int i = threadIdx.x; i < 2048; i += TPB){
    uintT u = s32[i];
    float v0 = fmaxf(bf2f((ushortT)(u & 0xffff))*sc.x + sc.y, 0.f);
    float v1 = fmaxf(bf2f((ushortT)(u >> 16))*sc.x + sc.y, 0.f);
    int idx = i*2;
    int row = idx >> 6, col = idx & 63;
    buf[row*65 + col]     = make_float2(v0, 0.f);
    buf[row*65 + col + 1] = make_float2(v1, 0.f);
  }
  __syncthreads();
  dft64ip<false>(W, buf);
  __syncthreads();
  dft64ip<true>(W, buf);
  __syncthreads();
  float2* dst = XH + ((size_t)bc*32 + zz)*2016;
  for (int idx = threadIdx.x; idx < 2016; idx += TPB){
    int mi = idx / 63, n = idx % 63;
    dst[idx] = buf[mi*65 + ((n+33)&63)];   // f1 = mi' for m'>=0
  }
}

// ---------------- F[bc,l,mi',n] (+)= sum_z qw*Dz[z,l,mi',n]*XH[bc,z,mi',n], 32-z chunk ----------------
__global__ __launch_bounds__(TPB) void k_wig_F(const float* __restrict__ Dz, const double* __restrict__ qw,
                                               const float2* __restrict__ XH, float2* __restrict__ F,
                                               int BC, int z0, int accum){
  __shared__ __attribute__((aligned(16))) float Dt[8192];       // [z32][l32][n8]
  __shared__ __attribute__((aligned(16))) float2 Xt[8*258];     // [bc8][z32*8+pad]
  int mi = blockIdx.x, nt = blockIdx.y;
  for (int idx = threadIdx.x; idx < 8192; idx += TPB){
    int z = idx >> 8, l = (idx >> 3) & 31, nn = idx & 7;
    int n = nt*8 + nn;
    float v = 0.f;
    if (n < 63) v = Dz[((size_t)((z0+z)*32 + l)*32 + mi)*63 + n] * (float)qw[z0+z];
    Dt[idx] = v;
  }
  int nch = (BC + 7) >> 3;
  int tid = threadIdx.x;
  int bcs = tid & 7, ng = (tid>>3)&1, lg = tid>>4;
  int l0 = lg*2, n0 = ng*4;
  for (int bcc = 0; bcc < nch; ++bcc){
    __syncthreads();
    for (int idx = tid; idx < 2048; idx += TPB){
      int bs = idx >> 8, z = (idx >> 3) & 31, nn = idx & 7;
      int bc = bcc*8 + bs, n = nt*8 + nn;
      float2 v = make_float2(0,0);
      if (bc < BC && n < 63) v = XH[((size_t)bc*32 + z)*2016 + mi*63 + n];
      Xt[bs*258 + z*8 + nn] = v;
    }
    __syncthreads();
    float2 acc[2][4];
    #pragma unroll
    for (int a = 0; a < 2; ++a)
      #pragma unroll
      for (int j = 0; j < 4; ++j) acc[a][j] = make_float2(0,0);
    for (int z = 0; z < 32; ++z){
      const float4* xp = (const float4*)&Xt[bcs*258 + z*8 + n0];
      float4 xa = xp[0], xb = xp[1];
      float xr[4] = {xa.x, xa.z, xb.x, xb.z};
      float xi[4] = {xa.y, xa.w, xb.y, xb.w};
      #pragma unroll
      for (int dl = 0; dl < 2; ++dl){
        const float4 d4 = *(const float4*)&Dt[(z*32 + l0 + dl)*8 + n0];
        float dd[4] = {d4.x, d4.y, d4.z, d4.w};
        #pragma unroll
        for (int j = 0; j < 4; ++j){
          acc[dl][j].x += dd[j]*xr[j];
          acc[dl][j].y += dd[j]*xi[j];
        }
      }
    }
    int bc = bcc*8 + bcs;
    if (bc < BC){
      #pragma unroll
      for (int dl = 0; dl < 2; ++dl){
        int l = l0 + dl;
        #pragma unroll
        for (int j = 0; j < 4; ++j){
          int n = nt*8 + n0 + j;
          if (n < 63){
            size_t a = ((size_t)(bc*32 + l))*2016 + mi*63 + n;
            float2 v = acc[dl][j];
            if (accum){ float2 old = F[a]; v.x += old.x; v.y += old.y; }
            F[a] = v;
          }
        }
      }
    }
  }
}

// ---------------- C[bi,l,mi',n] = sum_k F[bi,l,mi',k] * Deq[l][n][k] ----------------
__global__ __launch_bounds__(TPB) void k_deq_C(const float* __restrict__ Deq, const float2* __restrict__ F,
                                               float2* __restrict__ C, int BC){
  __shared__ float deq[63*65];     // [k][n]
  __shared__ float2 Fb[16*64];     // [bi16][k63 pad]
  int l = blockIdx.x, mi = blockIdx.y;
  for (int idx = threadIdx.x; idx < 3969; idx += TPB){
    int n = idx / 63, k = idx % 63;
    deq[k*65 + n] = Deq[((size_t)l*63 + n)*63 + k];
  }
  int nch = (BC + 15) >> 4;
  int tid = threadIdx.x;
  int bis = tid >> 4, nq = tid & 15, n0 = nq*4;
  for (int bic = 0; bic < nch; ++bic){
    __syncthreads();
    for (int idx = tid; idx < 1008; idx += TPB){
      int bs = idx / 63, k = idx % 63;
      int bi = bic*16 + bs;
      Fb[bs*64 + k] = (bi < BC) ? F[((size_t)(bi*32 + l))*2016 + mi*63 + k] : make_float2(0,0);
    }
    __syncthreads();
    float2 acc[4];
    #pragma unroll
    for (int j = 0; j < 4; ++j) acc[j] = make_float2(0,0);
    for (int k = 0; k < 63; ++k){
      float2 fv = Fb[bis*64 + k];
      #pragma unroll
      for (int j = 0; j < 4; ++j){
        int n = n0 + j;
        float d = (n < 63) ? deq[k*65 + n] : 0.f;
        acc[j].x += fv.x*d; acc[j].y += fv.y*d;
      }
    }
    int bi = bic*16 + bis;
    if (bi < BC){
      #pragma unroll
      for (int j = 0; j < 4; ++j){
        int n = n0 + j;
        if (n < 63) C[((size_t)(bi*32 + l))*2016 + mi*63 + n] = acc[j];
      }
    }
  }
}

// ---------------- Z[b,o,l,mi',n] = sum_i Kh[n,o,i] * C[b,i,l,mi',n] ----------------
__global__ __launch_bounds__(TPB) void k_kh_z(const float2* __restrict__ C, const float2* __restrict__ Kh,
                                              float2* __restrict__ Z, int I, int O){
  __shared__ float2 Kt[2700];   // [o][i]  (<=36*75)
  __shared__ float2 Ct[2400];   // [i][dl4][ms8]  (<=75*32)
  int n = blockIdx.x, b = blockIdx.y, l0 = blockIdx.z*4;
  int tid = threadIdx.x;
  for (int idx = tid; idx < O*I; idx += TPB)
    Kt[idx] = Kh[((size_t)n*O + (idx/I))*I + (idx%I)];
  int ms = tid & 7, og = tid >> 3;
  for (int mi0 = 0; mi0 < 32; mi0 += 8){
    __syncthreads();
    for (int idx = tid; idx < I*32; idx += TPB){
      int i = idx >> 5, dl = (idx >> 3) & 3, m2 = idx & 7;
      Ct[idx] = C[((size_t)((b*I + i)*32) + l0 + dl)*2016 + (mi0 + m2)*63 + n];
    }
    __syncthreads();
    #pragma unroll
    for (int rep = 0; rep < 2; ++rep){
      int o = og + rep*32;
      if (o < O){
        float2 acc[4];
        acc[0]=acc[1]=acc[2]=acc[3]=make_float2(0,0);
        for (int i = 0; i < I; ++i){
          float2 kh = Kt[o*I + i];
          #pragma unroll
          for (int dl = 0; dl < 4; ++dl){
            float2 cv = Ct[(i*4 + dl)*8 + ms];
            acc[dl].x += kh.x*cv.x - kh.y*cv.y;
            acc[dl].y += kh.x*cv.y + kh.y*cv.x;
          }
        }
        #pragma unroll
        for (int dl = 0; dl < 4; ++dl)
          Z[((size_t)((b*O + o)*32) + l0 + dl)*2016 + (mi0 + ms)*63 + n] = acc[dl];
      }
    }
  }
}

// ---------------- Xt[bo,z,mi',n] = sum_l (2l+1)/2 * Dz[z,l,mi',n] * Z[bo,l,mi',n] ----------------
__global__ __launch_bounds__(TPB) void k_wig_synth(const float* __restrict__ Dz, const float2* __restrict__ Z,
                                                   float2* __restrict__ Xt_g, int BO){
  __shared__ __attribute__((aligned(16))) float Dt[8192];       // [z32][l32][n8]
  __shared__ __attribute__((aligned(16))) float2 Zt[8*258];     // [bo8][l32*8+pad]
  int mi = blockIdx.x, nt = blockIdx.y, z0 = blockIdx.z*32;
  for (int idx = threadIdx.x; idx < 8192; idx += TPB){
    int z = idx >> 8, l = (idx >> 3) & 31, nn = idx & 7;
    int n = nt*8 + nn;
    float v = 0.f;
    if (n < 63) v = Dz[((size_t)((z0+z)*32 + l)*32 + mi)*63 + n] * (0.5f*(float)(2*l+1));
    Dt[idx] = v;
  }
  int nch = (BO + 7) >> 3;
  int tid = threadIdx.x;
  int bos = tid & 7, ng = (tid>>3)&1, zg = tid>>4;
  int zq = zg*2, n0 = ng*4;
  for (int boc = 0; boc < nch; ++boc){
    __syncthreads();
    for (int idx = tid; idx < 2048; idx += TPB){
      int bs = idx >> 8, l = (idx >> 3) & 31, nn = idx & 7;
      int bo = boc*8 + bs, n = nt*8 + nn;
      float2 v = make_float2(0,0);
      if (bo < BO && n < 63) v = Z[((size_t)bo*32 + l)*2016 + mi*63 + n];
      Zt[bs*258 + l*8 + nn] = v;
    }
    __syncthreads();
    float2 acc[2][4];
    #pragma unroll
    for (int a = 0; a < 2; ++a)
      #pragma unroll
      for (int j = 0; j < 4; ++j) acc[a][j] = make_float2(0,0);
    for (int l = 0; l < 32; ++l){
      const float4* xp = (const float4*)&Zt[bos*258 + l*8 + n0];
      float4 xa = xp[0], xb = xp[1];
      float zr[4] = {xa.x, xa.z, xb.x, xb.z};
      float zi[4] = {xa.y, xa.w, xb.y, xb.w};
      #pragma unroll
      for (int dz = 0; dz < 2; ++dz){
        const float4 d4 = *(const float4*)&Dt[((zq+dz)*32 + l)*8 + n0];
        float dd[4] = {d4.x, d4.y, d4.z, d4.w};
        #pragma unroll
        for (int j = 0; j < 4; ++j){
          acc[dz][j].x += dd[j]*zr[j];
          acc[dz][j].y += dd[j]*zi[j];
        }
      }
    }
    int bo = boc*8 + bos;
    if (bo < BO){
      #pragma unroll
      for (int dz = 0; dz < 2; ++dz){
        int z = z0 + zq + dz;
        #pragma unroll
        for (int j = 0; j < 4; ++j){
          int n = nt*8 + n0 + j;
          if (n < 63) Xt_g[((size_t)bo*64 + z)*2016 + mi*63 + n] = acc[dz][j];
        }
      }
    }
  }
}

// ---------------- build full plane from reduced Xt (Hermitian mirror) ----------------
__device__ void build_plane(const float2* __restrict__ src, float2* buf){
  for (int idx = threadIdx.x; idx < 4096; idx += TPB){
    int f1 = idx >> 6, f2 = idx & 63;
    int p1 = (f1 + 32) & 63, p2 = (f2 + 32) & 63;
    float2 v = make_float2(0,0);
    if (p1 != 0 && p2 != 0){
      int mi = p1 - 1, ni = p2 - 1;
      if (mi >= 31) v = src[(mi-31)*63 + ni];
      else { float2 t = src[(31-mi)*63 + (62-ni)]; v = make_float2(t.x, -t.y); }
    }
    buf[f1*65 + f2] = v;
  }
}

// ---------------- ifft2 + real + bias -> bf16 X ----------------
__global__ __launch_bounds__(TPB) void k_ifft2_sym(const float2* __restrict__ Xt, ushortT* __restrict__ Xo,
                                                   const float* __restrict__ bias, int O){
  __shared__ float2 W[64];
  __shared__ __attribute__((aligned(16))) float2 buf[64*65];
  int bo = blockIdx.x >> 6;
  int o = bo % O;
  if (threadIdx.x < 64){
    double ang = 2.0*PI_D*(double)threadIdx.x/64.0;
    W[threadIdx.x] = make_float2((float)cos(ang), (float)sin(ang));
  }
  const float2* src = Xt + (size_t)blockIdx.x*2016;
  build_plane(src, buf);
  __syncthreads();
  dft64ip<false>(W, buf);
  __syncthreads();
  dft64ip<true>(W, buf);
  __syncthreads();
  float bb = bias[o];
  ushortT* dst = Xo + (size_t)blockIdx.x*4096;
  for (int idx = threadIdx.x; idx < 4096; idx += TPB){
    int a = idx >> 6, g = idx & 63;
    dst[idx] = f2bf(buf[a*65 + g].x * (1.f/4096.f) + bb);
  }
}

// ---------------- conv3 final stats from spectrum (Parseval) ----------------
__global__ __launch_bounds__(TPB) void k_stats3(const float2* __restrict__ Xt, double* __restrict__ part){
  int bo = blockIdx.x, zb = blockIdx.y;
  double s = 0.0, p = 0.0;
  for (int zz = 0; zz < 4; ++zz){
    const float2* pl = Xt + ((size_t)bo*64 + zb*4 + zz)*2016;
    for (int idx = threadIdx.x; idx < 2016; idx += TPB){
      float2 v = pl[idx];
      double q = (double)v.x*v.x + (double)v.y*v.y;
      p += (idx < 63) ? q : 2.0*q;     // m'=0 row once, m'>0 rows twice
      if (idx == 31) s += v.x;          // DC (m=0,n=0)
    }
  }
  __shared__ double sh[TPB], sh2[TPB];
  sh[threadIdx.x] = s; sh2[threadIdx.x] = p;
  __syncthreads();
  for (int o = 128; o > 0; o >>= 1){
    if (threadIdx.x < o){ sh[threadIdx.x] += sh[threadIdx.x+o]; sh2[threadIdx.x] += sh2[threadIdx.x+o]; }
    __syncthreads();
  }
  if (threadIdx.x == 0){
    part[((size_t)bo*16 + zb)*2 + 0] = sh[0];
    part[((size_t)bo*16 + zb)*2 + 1] = sh2[0];
  }
}

__global__ void k_fstat(const double* __restrict__ part, const float* __restrict__ bias,
                        const float* __restrict__ g, const float* __restrict__ bsh,
                        float2* __restrict__ ss, int O){
  int o = threadIdx.x;
  if (o >= O) return;
  double S = 0.0, P = 0.0;
  for (int b = 0; b < 2; ++b)
    for (int zb = 0; zb < 16; ++zb){
      size_t base = ((size_t)(b*O + o)*16 + zb)*2;
      S += part[base]; P += part[base+1];
    }
  P *= (1.0/4096.0);
  double N = 524288.0;
  double bi = bias[o];
  double mean = S/N + bi;
  double var = P/N + 2.0*bi*S/N + bi*bi - mean*mean;
  double sc = (double)g[o] / sqrt(var + 1e-5);
  ss[o] = make_float2((float)sc, (float)((bi - mean)*sc + (double)bsh[o]));
}

// ---------------- fused ifft2 + BN + ReLU + mean over gamma ----------------
__global__ __launch_bounds__(TPB) void k_final(const float2* __restrict__ Xt, const float2* __restrict__ ss,
                                               float* __restrict__ out, int O){
  __shared__ float2 W[64];
  __shared__ __attribute__((aligned(16))) float2 buf[64*65];
  __shared__ float srow[64];
  int bo = blockIdx.x >> 6;
  int o = bo % O;
  if (threadIdx.x < 64){
    double ang = 2.0*PI_D*(double)threadIdx.x/64.0;
    W[threadIdx.x] = make_float2((float)cos(ang), (float)sin(ang));
  }
  const float2* src = Xt + (size_t)blockIdx.x*2016;
  build_plane(src, buf);
  __syncthreads();
  dft64ip<false>(W, buf);
  __syncthreads();
  dft64ip<true>(W, buf);
  __syncthreads();
  float2 sv = ss[o];
  int w = threadIdx.x >> 6;
  int lane = threadIdx.x & 63;
  for (int k = 0; k < 16; ++k){
    int a = k*4 + w;
    float v = fmaxf(fmaf(buf[a*65 + lane].x*(1.f/4096.f), sv.x, sv.y), 0.f);
    for (int off = 32; off; off >>= 1) v += __shfl_down(v, off);
    if (lane == 0) srow[a] = v;
  }
  __syncthreads();
  if (threadIdx.x < 64) out[(size_t)blockIdx.x*64 + threadIdx.x] = srow[threadIdx.x]*(1.f/64.f);
}

extern "C" void kernel_launch(void* const* d_in, const int* in_sizes, int n_in,
                              void* d_out, int out_size, void* d_ws, size_t ws_size,
                              hipStream_t stream){
  const float* x   = (const float*)d_in[0];
  const float* ks2 = (const float*)d_in[1];
  const float* bs2 = (const float*)d_in[2];
  const float* k1  = (const float*)d_in[3];
  const float* b1c = (const float*)d_in[4];
  const float* k2  = (const float*)d_in[5];
  const float* b2c = (const float*)d_in[6];
  const float* k3  = (const float*)d_in[7];
  const float* b3c = (const float*)d_in[8];
  const float* g1 = (const float*)d_in[9],  *bb1 = (const float*)d_in[10];
  const float* g2 = (const float*)d_in[11], *bb2 = (const float*)d_in[12];
  const float* g3 = (const float*)d_in[13], *bb3 = (const float*)d_in[14];
  const float* g4 = (const float*)d_in[15], *bb4 = (const float*)d_in[16];
  float* out = (float*)d_out;

  char* w = (char*)d_ws;
  size_t off = 0;
  auto take = [&](size_t bytes)->char*{
    char* p = w + off;
    off += (bytes + 255) & ~(size_t)255;
    return p;
  };
  float*  Dz   = (float*) take(64ull*32*32*63*4);     // 16.5 MB
  float*  Deq  = (float*) take(32ull*63*63*4);        // 0.5 MB
  double* lf   = (double*)take(65*8);
  double* qw   = (double*)take(64*8);
  double* part = (double*)take(75ull*64*2*8);
  float2* ss   = (float2*)take(75*8);
  float2* KhS2 = (float2*)take(63ull*25*3*8);
  float2* Kh1  = (float2*)take(63ull*25*25*8);
  float2* Kh2  = (float2*)take(63ull*25*50*8);
  float2* Kh3  = (float2*)take(63ull*36*75*8);
  float2* XH2  = (float2*)take(2ull*3*64*63*8);
  float2* F2   = (float2*)take(2ull*3*32*63*8);
  ushortT* X1  = (ushortT*)take(2ull*25*262144*2);    // 26.2 MB bf16
  ushortT* X2  = (ushortT*)take(2ull*25*262144*2);
  ushortT* X3  = (ushortT*)take(2ull*25*262144*2);
  float2* A    = (float2*)take(150ull*32*2016*8);     // 77.4 MB
  float2* B    = (float2*)take(150ull*32*2016*8);     // 77.4 MB
  if (off > ws_size) return;

  dim3 tpb(TPB);
  auto cdiv = [](long long a, long long b){ return (int)((a + b - 1) / b); };

  k_tables<<<1, 64, 0, stream>>>(lf, qw);
  k_wigner<<<dim3(65,32), tpb, 0, stream>>>(lf, Dz, Deq);
  k_kh<<<cdiv(3ll*25*63,TPB),  tpb, 0, stream>>>(ks2, KhS2, 3, 25,  (float)(1.0/sqrt(196608.0)));
  k_kh<<<cdiv(25ll*25*63,TPB), tpb, 0, stream>>>(k1,  Kh1, 25, 25, (float)(1.0/sqrt(1600.0)));
  k_kh<<<cdiv(50ll*25*63,TPB), tpb, 0, stream>>>(k2,  Kh2, 50, 25, (float)(1.0/sqrt(3200.0)));
  k_kh<<<cdiv(75ll*36*63,TPB), tpb, 0, stream>>>(k3,  Kh3, 75, 36, (float)(1.0/sqrt(4800.0)));

  // ---- S2 conv ----
  k_s2_fft<<<cdiv(2ll*3*64*63,TPB), tpb, 0, stream>>>(x, XH2);
  k_s2_F<<<cdiv(2ll*3*32*63,TPB), tpb, 0, stream>>>(Dz, qw, XH2, F2);
  k_s2_zhat<<<cdiv(2ll*25*32*2016,TPB), tpb, 0, stream>>>(Deq, F2, KhS2, B);
  k_wig_synth<<<dim3(32,8,2), tpb, 0, stream>>>(Dz, B, A, 50);
  k_ifft2_sym<<<50*64, tpb, 0, stream>>>(A, X1, bs2, 25);

  // ---- generic SO3 conv ----
  auto so3 = [&](const ushortT* Xa, const ushortT* Xb, const ushortT* Xc, int Cin,
                 const float* g, const float* bb, const float2* Kh, int O,
                 const float* bias, ushortT* Xout, int isFinal){
    int BC = 2*Cin, BO = 2*O;
    k_bnstats<<<dim3(25,64), tpb, 0, stream>>>(Xa, 0, part);
    if (Cin > 25) k_bnstats<<<dim3(25,64), tpb, 0, stream>>>(Xb, 25, part);
    if (Cin > 50) k_bnstats<<<dim3(25,64), tpb, 0, stream>>>(Xc, 50, part);
    k_bnfinal<<<1, 128, 0, stream>>>(part, g, bb, ss, Cin);
    for (int z0 = 0; z0 < 64; z0 += 32){
      k_fft2_fwd<<<dim3(BC,32), tpb, 0, stream>>>(Xa, Xb, Xc, ss, A, Cin, z0);
      k_wig_F<<<dim3(32,8), tpb, 0, stream>>>(Dz, qw, A, B, BC, z0, z0 > 0 ? 1 : 0);
    }
    k_deq_C<<<dim3(32,32), tpb, 0, stream>>>(Deq, B, A, BC);
    k_kh_z<<<dim3(63,2,8), tpb, 0, stream>>>(A, Kh, B, Cin, O);
    k_wig_synth<<<dim3(32,8,2), tpb, 0, stream>>>(Dz, B, A, BO);
    if (!isFinal){
      k_ifft2_sym<<<BO*64, tpb, 0, stream>>>(A, Xout, bias, O);
    } else {
      k_stats3<<<dim3(BO,16), tpb, 0, stream>>>(A, part);
      k_fstat<<<1, 64, 0, stream>>>(part, bias, g4, bb4, ss, O);
      k_final<<<BO*64, tpb, 0, stream>>>(A, ss, out, O);
    }
  };

  so3(X1, X1, X1, 25, g1, bb1, Kh1, 25, b1c, X2, 0);
  so3(X1, X2, X2, 50, g2, bb2, Kh2, 25, b2c, X3, 0);
  so3(X1, X2, X3, 75, g3, bb3, Kh3, 36, b3c, nullptr, 1);
}

// Round 3
// 3701.232 us; speedup vs baseline: 1.3840x; 1.3840x over previous
//
#include <hip/hip_runtime.h>
#include <math.h>

#define PI_D 3.14159265358979323846
#define TPB 256
typedef unsigned short ushortT;
typedef unsigned int uintT;

__device__ __forceinline__ float2 cxmul(float2 a, float2 b){
  return make_float2(a.x*b.x - a.y*b.y, a.x*b.y + a.y*b.x);
}
__device__ __forceinline__ float bf2f(ushortT u){
  uintT x = ((uintT)u) << 16;
  return __uint_as_float(x);
}
__device__ __forceinline__ ushortT f2bf(float f){
  uintT x = __float_as_uint(f);
  x = x + 0x7FFFu + ((x >> 16) & 1u);
  return (ushortT)(x >> 16);
}

// ---------------- tables ----------------
__global__ void k_tables(double* lf, double* qw){
  if (threadIdx.x == 0){
    lf[0] = 0.0;
    for (int i = 1; i <= 64; ++i) lf[i] = lf[i-1] + log((double)i);
  }
  int j = threadIdx.x;
  if (j < 64){
    double s1 = sin(PI_D*(2*j+1)/128.0);
    double inner = 0.0;
    for (int k = 0; k < 32; ++k)
      inner += (1.0/(double)(2*k+1)) * sin((double)(2*j+1)*(double)(2*k+1)*PI_D/128.0);
    qw[j] = (2.0/32.0) * s1 * inner;
  }
}

__device__ double wigd(const double* lfs, int l, int mp, int m, double lc, double ls){
  if (mp < -l || mp > l || m < -l || m > l) return 0.0;
  int k0 = (m - mp > 0) ? (m - mp) : 0;
  int k1 = (l + m < l - mp) ? (l + m) : (l - mp);
  double base = 0.5*(lfs[l+mp] + lfs[l-mp] + lfs[l+m] + lfs[l-m]);
  double val = 0.0;
  for (int k = k0; k <= k1; ++k){
    double t = base - lfs[l+m-k] - lfs[k] - lfs[mp-m+k] - lfs[l-mp-k]
             + (double)(2*l + m - mp - 2*k)*lc + (double)(mp - m + 2*k)*ls;
    double e = exp(t);
    val += ((mp - m + k) & 1) ? -e : e;
  }
  return val;
}

// Dz[z][l][mi'][n]: d^l_{mi', n-31}(beta_z) for mi' in 0..31, n full 0..62
// Deq[l][r][c]: d^l_{r-31, c-31}(pi/2) full
__global__ __launch_bounds__(TPB) void k_wigner(const double* __restrict__ lf,
                                                float* __restrict__ Dz, float* __restrict__ Deq){
  __shared__ double lfs[65];
  if (threadIdx.x < 65) lfs[threadIdx.x] = lf[threadIdx.x];
  __syncthreads();
  int zs = blockIdx.x, l = blockIdx.y;
  double beta = (zs < 64) ? ((double)zs + 0.5)*PI_D/64.0 : PI_D*0.5;
  double ch = cos(beta*0.5), sh = sin(beta*0.5);
  double lc = log(ch), ls = log(sh);
  if (zs < 64){
    for (int idx = threadIdx.x; idx < 2016; idx += TPB){
      int mi = idx/63, c = idx%63;
      Dz[((size_t)(zs*32 + l)*32 + mi)*63 + c] = (float)wigd(lfs, l, mi, c-31, lc, ls);
    }
  } else {
    for (int idx = threadIdx.x; idx < 3969; idx += TPB){
      int r = idx/63, c = idx%63;
      Deq[((size_t)l*63 + r)*63 + c] = (float)wigd(lfs, l, r-31, c-31, lc, ls);
    }
  }
}

// Kh[n][o][i] = scale * sum_p K[i,o,p] * exp(-i*2pi*p*(n-31)/64)
__global__ void k_kh(const float* __restrict__ K, float2* __restrict__ Kh, int I, int O, float scale){
  int idx = blockIdx.x*blockDim.x + threadIdx.x;
  int total = I*O*63;
  if (idx >= total) return;
  int i = idx % I, o = (idx / I) % O, n = idx / (I*O);
  float sr = 0.f, si = 0.f;
  for (int p = 0; p < 64; ++p){
    int t = (p * (n - 31)) & 63;
    float s, c;
    sincosf(-(float)PI_D/32.f * (float)t, &s, &c);
    float kv = K[(i*O + o)*64 + p];
    sr += kv * c; si += kv * s;
  }
  Kh[((size_t)n*O + o)*I + i] = make_float2(sr*scale, si*scale);
}

// ---------------- S2 front ----------------
__global__ void k_s2_fft(const float* __restrict__ x, float2* __restrict__ XH2){
  int idx = blockIdx.x*blockDim.x + threadIdx.x;
  if (idx >= 2*3*64*63) return;
  int mi = idx % 63; int z = (idx/63) & 63; int bc = idx / (63*64);
  int f = (mi + 33) & 63;
  const float* row = x + ((size_t)bc*64 + z)*64;
  float sr = 0.f, si = 0.f;
  for (int a = 0; a < 64; ++a){
    int t = (f*a) & 63;
    float s, c;
    sincosf(-(float)PI_D/32.f * (float)t, &s, &c);
    sr += row[a]*c; si += row[a]*s;
  }
  XH2[idx] = make_float2(sr, si);
}

__global__ void k_s2_F(const float* __restrict__ Dz, const double* __restrict__ qw,
                       const float2* __restrict__ XH2, float2* __restrict__ F2){
  int idx = blockIdx.x*blockDim.x + threadIdx.x;
  if (idx >= 2*3*32*63) return;
  int r = idx % 63; int l = (idx/63) & 31; int bc = idx / (63*32);
  float2 acc = make_float2(0,0);
  for (int z = 0; z < 64; ++z){
    float d;
    if (r >= 31) d = Dz[((size_t)(z*32 + l)*32 + (r-31))*63 + 31];
    else {
      d = Dz[((size_t)(z*32 + l)*32 + (31-r))*63 + 31];
      if ((31-r) & 1) d = -d;
    }
    float wv = (float)qw[z] * d;
    float2 v = XH2[((size_t)bc*64 + z)*63 + r];
    acc.x += wv*v.x; acc.y += wv*v.y;
  }
  F2[idx] = acc;
}

__global__ void k_s2_zhat(const float* __restrict__ Deq, const float2* __restrict__ F2,
                          const float2* __restrict__ Kh, float2* __restrict__ Z){
  int idx = blockIdx.x*blockDim.x + threadIdx.x;
  if (idx >= 2*25*32*2016) return;
  int n = idx % 63; int mi = (idx/63) & 31; int l = (idx/2016) & 31;
  int o = (idx/(2016*32)) % 25; int b = idx/(2016*32*25);
  float deq0 = Deq[((size_t)l*63 + n)*63 + 31];
  float2 acc = make_float2(0,0);
  for (int i = 0; i < 3; ++i){
    float2 f = F2[((size_t)(b*3 + i)*32 + l)*63 + (mi+31)];
    float2 kh = Kh[((size_t)n*25 + o)*3 + i];
    float2 p = cxmul(f, kh);
    acc.x += p.x; acc.y += p.y;
  }
  Z[((size_t)((b*25+o)*32) + l)*2016 + mi*63 + n] = make_float2(acc.x*deq0, acc.y*deq0);
}

// ---------------- BN stats over bf16 X buffers ----------------
__global__ __launch_bounds__(TPB) void k_bnstats(const ushortT* __restrict__ src, int slotBase,
                                                 double* __restrict__ part){
  int c = blockIdx.x, blk = blockIdx.y;
  const uint2* s4 = (const uint2*)src;
  double s = 0.0, q = 0.0;
  for (int k = 0; k < 8; ++k){
    int g4 = blk*2048 + k*256 + threadIdx.x;
    int b = g4 >> 16, pos4 = g4 & 65535;
    uint2 u = s4[((size_t)(b*25 + c))*65536 + pos4];
    float v0 = bf2f((ushortT)(u.x & 0xffff)), v1 = bf2f((ushortT)(u.x >> 16));
    float v2 = bf2f((ushortT)(u.y & 0xffff)), v3 = bf2f((ushortT)(u.y >> 16));
    s += (double)v0 + v1 + v2 + v3;
    q += (double)v0*v0 + (double)v1*v1 + (double)v2*v2 + (double)v3*v3;
  }
  __shared__ double sh[TPB], sh2[TPB];
  sh[threadIdx.x] = s; sh2[threadIdx.x] = q;
  __syncthreads();
  for (int o = 128; o > 0; o >>= 1){
    if (threadIdx.x < o){ sh[threadIdx.x] += sh[threadIdx.x+o]; sh2[threadIdx.x] += sh2[threadIdx.x+o]; }
    __syncthreads();
  }
  if (threadIdx.x == 0){
    part[((size_t)(slotBase + c)*64 + blk)*2 + 0] = sh[0];
    part[((size_t)(slotBase + c)*64 + blk)*2 + 1] = sh2[0];
  }
}

__global__ void k_bnfinal(const double* __restrict__ part, const float* __restrict__ g,
                          const float* __restrict__ b, float2* __restrict__ ss, int C){
  int c = blockIdx.x*blockDim.x + threadIdx.x;
  if (c >= C) return;
  double s = 0.0, q = 0.0;
  for (int k = 0; k < 64; ++k){
    s += part[((size_t)c*64 + k)*2 + 0];
    q += part[((size_t)c*64 + k)*2 + 1];
  }
  double N = 524288.0;
  double mu = s / N;
  double var = q / N - mu*mu;
  double sc = (double)g[c] / sqrt(var + 1e-5);
  ss[c] = make_float2((float)sc, (float)((double)b[c] - mu*sc));
}

// ---------------- 64-pt FFT across lanes (radix-2 DIF, 6 stages, shfl) ----------------
// Input: lane n holds x[n]. Output: lane n holds X[bitrev6(n)].
__device__ __forceinline__ float2 fft64_lane(float2 x, const float2* __restrict__ Wt, int lane){
  #pragma unroll
  for (int st = 0; st < 6; ++st){
    int h = 32 >> st;
    float2 p;
    p.x = __shfl_xor(x.x, h, 64);
    p.y = __shfl_xor(x.y, h, 64);
    if (lane & h){
      float2 s = make_float2(p.x - x.x, p.y - x.y);
      x = cxmul(s, Wt[(lane & (h-1)) << st]);
    } else {
      x = make_float2(x.x + p.x, x.y + p.y);
    }
  }
  return x;
}

// build W table: sign=-1 forward, +1 inverse
__device__ __forceinline__ void init_W(float2* W, float sign){
  if (threadIdx.x < 64){
    float s, c;
    sincosf(sign*(float)(2.0*PI_D/64.0)*(float)threadIdx.x, &s, &c);
    W[threadIdx.x] = make_float2(c, s);
  }
}

// ---------------- fused BN+ReLU + fft2 + reduced centered extraction ----------------
__global__ __launch_bounds__(TPB) void k_fft2_fwd(const ushortT* __restrict__ X1, const ushortT* __restrict__ X2,
                                                  const ushortT* __restrict__ X3, const float2* __restrict__ ss,
                                                  float2* __restrict__ XH, int Cin, int z0){
  __shared__ float2 W[64];
  __shared__ __attribute__((aligned(16))) float2 buf[64*65];
  int bc = blockIdx.x, zz = blockIdx.y, z = z0 + zz;
  int b = bc / Cin, ci = bc % Cin;
  const ushortT* src; int cl;
  if (ci < 25){ src = X1; cl = ci; }
  else if (ci < 50){ src = X2; cl = ci - 25; }
  else { src = X3; cl = ci - 50; }
  src += ((size_t)(b*25 + cl)*64 + z)*4096;
  float2 sc = ss[ci];
  init_W(W, -1.f);
  int tid = threadIdx.x, lane = tid & 63, wid = tid >> 6;
  int rl = (int)(__brev((uintT)lane) >> 26);
  const uintT* s32 = (const uintT*)src;
  for (int i = tid; i < 2048; i += TPB){
    uintT u = s32[i];
    float v0 = fmaxf(bf2f((ushortT)(u & 0xffff))*sc.x + sc.y, 0.f);
    float v1 = fmaxf(bf2f((ushortT)(u >> 16))*sc.x + sc.y, 0.f);
    int row = i >> 5, col = (i << 1) & 63;
    buf[row*65 + col]     = make_float2(v0, 0.f);
    buf[row*65 + col + 1] = make_float2(v1, 0.f);
  }
  __syncthreads();
  // row pass (over alpha2)
  #pragma unroll 4
  for (int i = 0; i < 16; ++i){
    int r = wid*16 + i;
    float2 x = buf[r*65 + lane];
    x = fft64_lane(x, W, lane);
    buf[r*65 + rl] = x;
  }
  __syncthreads();
  // col pass (over alpha1)
  #pragma unroll 4
  for (int i = 0; i < 16; ++i){
    int c = wid*16 + i;
    float2 x = buf[lane*65 + c];
    x = fft64_lane(x, W, lane);
    buf[rl*65 + c] = x;
  }
  __syncthreads();
  float2* dst = XH + ((size_t)bc*32 + zz)*2016;
  for (int idx = tid; idx < 2016; idx += TPB){
    int mi = idx / 63, n = idx % 63;
    dst[idx] = buf[mi*65 + ((n+33)&63)];
  }
}

// ---------------- F[bc,l,mi',n] (+)= sum_z qw*Dz*XH, 32-z chunk, bc-chunk-split grid ----------------
__global__ __launch_bounds__(TPB) void k_wig_F(const float* __restrict__ Dz, const double* __restrict__ qw,
                                               const float2* __restrict__ XH, float2* __restrict__ F,
                                               int BC, int z0, int accum, int nch){
  __shared__ __attribute__((aligned(16))) float Dt[8192];       // [z32][l32][n8]
  __shared__ __attribute__((aligned(16))) float2 Xt[8*258];     // [bc8][z32*8+pad]
  int mi = blockIdx.x, nt = blockIdx.y;
  int c0 = blockIdx.z*4, c1 = (c0+4 < nch) ? c0+4 : nch;
  for (int idx = threadIdx.x; idx < 8192; idx += TPB){
    int z = idx >> 8, l = (idx >> 3) & 31, nn = idx & 7;
    int n = nt*8 + nn;
    float v = 0.f;
    if (n < 63) v = Dz[((size_t)((z0+z)*32 + l)*32 + mi)*63 + n] * (float)qw[z0+z];
    Dt[idx] = v;
  }
  int tid = threadIdx.x;
  int bcs = tid & 7, ng = (tid>>3)&1, lg = tid>>4;
  int l0 = lg*2, n0 = ng*4;
  for (int bcc = c0; bcc < c1; ++bcc){
    __syncthreads();
    for (int idx = tid; idx < 2048; idx += TPB){
      int bs = idx >> 8, z = (idx >> 3) & 31, nn = idx & 7;
      int bc = bcc*8 + bs, n = nt*8 + nn;
      float2 v = make_float2(0,0);
      if (bc < BC && n < 63) v = XH[((size_t)bc*32 + z)*2016 + mi*63 + n];
      Xt[bs*258 + z*8 + nn] = v;
    }
    __syncthreads();
    float2 acc[2][4];
    #pragma unroll
    for (int a = 0; a < 2; ++a)
      #pragma unroll
      for (int j = 0; j < 4; ++j) acc[a][j] = make_float2(0,0);
    for (int z = 0; z < 32; ++z){
      const float4* xp = (const float4*)&Xt[bcs*258 + z*8 + n0];
      float4 xa = xp[0], xb = xp[1];
      float xr[4] = {xa.x, xa.z, xb.x, xb.z};
      float xi[4] = {xa.y, xa.w, xb.y, xb.w};
      #pragma unroll
      for (int dl = 0; dl < 2; ++dl){
        const float4 d4 = *(const float4*)&Dt[(z*32 + l0 + dl)*8 + n0];
        float dd[4] = {d4.x, d4.y, d4.z, d4.w};
        #pragma unroll
        for (int j = 0; j < 4; ++j){
          acc[dl][j].x += dd[j]*xr[j];
          acc[dl][j].y += dd[j]*xi[j];
        }
      }
    }
    int bc = bcc*8 + bcs;
    if (bc < BC){
      #pragma unroll
      for (int dl = 0; dl < 2; ++dl){
        int l = l0 + dl;
        #pragma unroll
        for (int j = 0; j < 4; ++j){
          int n = nt*8 + n0 + j;
          if (n < 63){
            size_t a = ((size_t)(bc*32 + l))*2016 + mi*63 + n;
            float2 v = acc[dl][j];
            if (accum){ float2 old = F[a]; v.x += old.x; v.y += old.y; }
            F[a] = v;
          }
        }
      }
    }
  }
}

// ---------------- C[bi,l,mi',n] = sum_k F[bi,l,mi',k] * Deq[l][n][k] ----------------
__global__ __launch_bounds__(TPB) void k_deq_C(const float* __restrict__ Deq, const float2* __restrict__ F,
                                               float2* __restrict__ C, int BC){
  __shared__ float deq[63*65];
  __shared__ float2 Fb[16*64];
  int l = blockIdx.x, mi = blockIdx.y;
  for (int idx = threadIdx.x; idx < 3969; idx += TPB){
    int n = idx / 63, k = idx % 63;
    deq[k*65 + n] = Deq[((size_t)l*63 + n)*63 + k];
  }
  int nch = (BC + 15) >> 4;
  int tid = threadIdx.x;
  int bis = tid >> 4, nq = tid & 15, n0 = nq*4;
  for (int bic = 0; bic < nch; ++bic){
    __syncthreads();
    for (int idx = tid; idx < 1008; idx += TPB){
      int bs = idx / 63, k = idx % 63;
      int bi = bic*16 + bs;
      Fb[bs*64 + k] = (bi < BC) ? F[((size_t)(bi*32 + l))*2016 + mi*63 + k] : make_float2(0,0);
    }
    __syncthreads();
    float2 acc[4];
    #pragma unroll
    for (int j = 0; j < 4; ++j) acc[j] = make_float2(0,0);
    for (int k = 0; k < 63; ++k){
      float2 fv = Fb[bis*64 + k];
      #pragma unroll
      for (int j = 0; j < 4; ++j){
        int n = n0 + j;
        float d = (n < 63) ? deq[k*65 + n] : 0.f;
        acc[j].x += fv.x*d; acc[j].y += fv.y*d;
      }
    }
    int bi = bic*16 + bis;
    if (bi < BC){
      #pragma unroll
      for (int j = 0; j < 4; ++j){
        int n = n0 + j;
        if (n < 63) C[((size_t)(bi*32 + l))*2016 + mi*63 + n] = acc[j];
      }
    }
  }
}

// ---------------- Z[b,o,l,mi',n] = sum_i Kh[n,o,i] * C[b,i,l,mi',n] ----------------
__global__ __launch_bounds__(TPB) void k_kh_z(const float2* __restrict__ C, const float2* __restrict__ Kh,
                                              float2* __restrict__ Z, int I, int O){
  __shared__ float2 Kt[2700];
  __shared__ float2 Ct[2400];
  int n = blockIdx.x, b = blockIdx.y, l0 = blockIdx.z*4;
  int tid = threadIdx.x;
  for (int idx = tid; idx < O*I; idx += TPB)
    Kt[idx] = Kh[((size_t)n*O + (idx/I))*I + (idx%I)];
  int ms = tid & 7, og = tid >> 3;
  for (int mi0 = 0; mi0 < 32; mi0 += 8){
    __syncthreads();
    for (int idx = tid; idx < I*32; idx += TPB){
      int i = idx >> 5, dl = (idx >> 3) & 3, m2 = idx & 7;
      Ct[idx] = C[((size_t)((b*I + i)*32) + l0 + dl)*2016 + (mi0 + m2)*63 + n];
    }
    __syncthreads();
    #pragma unroll
    for (int rep = 0; rep < 2; ++rep){
      int o = og + rep*32;
      if (o < O){
        float2 acc[4];
        acc[0]=acc[1]=acc[2]=acc[3]=make_float2(0,0);
        for (int i = 0; i < I; ++i){
          float2 kh = Kt[o*I + i];
          #pragma unroll
          for (int dl = 0; dl < 4; ++dl){
            float2 cv = Ct[(i*4 + dl)*8 + ms];
            acc[dl].x += kh.x*cv.x - kh.y*cv.y;
            acc[dl].y += kh.x*cv.y + kh.y*cv.x;
          }
        }
        #pragma unroll
        for (int dl = 0; dl < 4; ++dl)
          Z[((size_t)((b*O + o)*32) + l0 + dl)*2016 + (mi0 + ms)*63 + n] = acc[dl];
      }
    }
  }
}

// ---------------- Xt[bo,z,mi',n] = sum_l (2l+1)/2 * Dz * Z, bo-chunk-split grid ----------------
__global__ __launch_bounds__(TPB) void k_wig_synth(const float* __restrict__ Dz, const float2* __restrict__ Z,
                                                   float2* __restrict__ Xt_g, int BO, int nch){
  __shared__ __attribute__((aligned(16))) float Dt[8192];
  __shared__ __attribute__((aligned(16))) float2 Zt[8*258];
  int mi = blockIdx.x, nt = blockIdx.y;
  int z0 = (blockIdx.z & 1)*32;
  int c0 = (blockIdx.z >> 1)*4, c1 = (c0+4 < nch) ? c0+4 : nch;
  for (int idx = threadIdx.x; idx < 8192; idx += TPB){
    int z = idx >> 8, l = (idx >> 3) & 31, nn = idx & 7;
    int n = nt*8 + nn;
    float v = 0.f;
    if (n < 63) v = Dz[((size_t)((z0+z)*32 + l)*32 + mi)*63 + n] * (0.5f*(float)(2*l+1));
    Dt[idx] = v;
  }
  int tid = threadIdx.x;
  int bos = tid & 7, ng = (tid>>3)&1, zg = tid>>4;
  int zq = zg*2, n0 = ng*4;
  for (int boc = c0; boc < c1; ++boc){
    __syncthreads();
    for (int idx = tid; idx < 2048; idx += TPB){
      int bs = idx >> 8, l = (idx >> 3) & 31, nn = idx & 7;
      int bo = boc*8 + bs, n = nt*8 + nn;
      float2 v = make_float2(0,0);
      if (bo < BO && n < 63) v = Z[((size_t)bo*32 + l)*2016 + mi*63 + n];
      Zt[bs*258 + l*8 + nn] = v;
    }
    __syncthreads();
    float2 acc[2][4];
    #pragma unroll
    for (int a = 0; a < 2; ++a)
      #pragma unroll
      for (int j = 0; j < 4; ++j) acc[a][j] = make_float2(0,0);
    for (int l = 0; l < 32; ++l){
      const float4* xp = (const float4*)&Zt[bos*258 + l*8 + n0];
      float4 xa = xp[0], xb = xp[1];
      float zr[4] = {xa.x, xa.z, xb.x, xb.z};
      float zi[4] = {xa.y, xa.w, xb.y, xb.w};
      #pragma unroll
      for (int dz = 0; dz < 2; ++dz){
        const float4 d4 = *(const float4*)&Dt[((zq+dz)*32 + l)*8 + n0];
        float dd[4] = {d4.x, d4.y, d4.z, d4.w};
        #pragma unroll
        for (int j = 0; j < 4; ++j){
          acc[dz][j].x += dd[j]*zr[j];
          acc[dz][j].y += dd[j]*zi[j];
        }
      }
    }
    int bo = boc*8 + bos;
    if (bo < BO){
      #pragma unroll
      for (int dz = 0; dz < 2; ++dz){
        int z = z0 + zq + dz;
        #pragma unroll
        for (int j = 0; j < 4; ++j){
          int n = nt*8 + n0 + j;
          if (n < 63) Xt_g[((size_t)bo*64 + z)*2016 + mi*63 + n] = acc[dz][j];
        }
      }
    }
  }
}

// ---------------- coalesced Hermitian build: reduced spectrum -> full 64x64 plane ----------------
__device__ __forceinline__ void build_plane_c(const float2* __restrict__ src, float2* buf){
  int tid = threadIdx.x;
  if (tid < 128){
    int k = tid & 63;
    if (tid < 64) buf[32*65 + k] = make_float2(0,0);
    else          buf[k*65 + 32] = make_float2(0,0);
  }
  for (int idx = tid; idx < 2016; idx += TPB){
    float2 v = src[idx];
    int mi = idx / 63, ni = idx - mi*63;
    buf[mi*65 + ((ni+33)&63)] = v;
    if (mi > 0) buf[(64-mi)*65 + ((31-ni)&63)] = make_float2(v.x, -v.y);
  }
}

// ---------------- ifft2 + real + bias -> bf16 X ----------------
__global__ __launch_bounds__(TPB) void k_ifft2_sym(const float2* __restrict__ Xt, ushortT* __restrict__ Xo,
                                                   const float* __restrict__ bias, int O){
  __shared__ float2 W[64];
  __shared__ __attribute__((aligned(16))) float2 buf[64*65];
  int bo = blockIdx.x >> 6;
  int o = bo % O;
  init_W(W, 1.f);
  int tid = threadIdx.x, lane = tid & 63, wid = tid >> 6;
  int rl = (int)(__brev((uintT)lane) >> 26);
  const float2* src = Xt + (size_t)blockIdx.x*2016;
  build_plane_c(src, buf);
  __syncthreads();
  #pragma unroll 4
  for (int i = 0; i < 16; ++i){
    int r = wid*16 + i;
    float2 x = buf[r*65 + lane];
    x = fft64_lane(x, W, lane);
    buf[r*65 + rl] = x;
  }
  __syncthreads();
  #pragma unroll 4
  for (int i = 0; i < 16; ++i){
    int c = wid*16 + i;
    float2 x = buf[lane*65 + c];
    x = fft64_lane(x, W, lane);
    buf[rl*65 + c] = x;
  }
  __syncthreads();
  float bb = bias[o];
  ushortT* dst = Xo + (size_t)blockIdx.x*4096;
  for (int idx = tid; idx < 4096; idx += TPB){
    dst[idx] = f2bf(buf[(idx>>6)*65 + (idx&63)].x * (1.f/4096.f) + bb);
  }
}

// ---------------- conv3 final stats from spectrum (Parseval) ----------------
__global__ __launch_bounds__(TPB) void k_stats3(const float2* __restrict__ Xt, double* __restrict__ part){
  int bo = blockIdx.x, zb = blockIdx.y;
  double s = 0.0, p = 0.0;
  for (int zz = 0; zz < 4; ++zz){
    const float2* pl = Xt + ((size_t)bo*64 + zb*4 + zz)*2016;
    for (int idx = threadIdx.x; idx < 2016; idx += TPB){
      float2 v = pl[idx];
      double q = (double)v.x*v.x + (double)v.y*v.y;
      p += (idx < 63) ? q : 2.0*q;
      if (idx == 31) s += v.x;
    }
  }
  __shared__ double sh[TPB], sh2[TPB];
  sh[threadIdx.x] = s; sh2[threadIdx.x] = p;
  __syncthreads();
  for (int o = 128; o > 0; o >>= 1){
    if (threadIdx.x < o){ sh[threadIdx.x] += sh[threadIdx.x+o]; sh2[threadIdx.x] += sh2[threadIdx.x+o]; }
    __syncthreads();
  }
  if (threadIdx.x == 0){
    part[((size_t)bo*16 + zb)*2 + 0] = sh[0];
    part[((size_t)bo*16 + zb)*2 + 1] = sh2[0];
  }
}

__global__ void k_fstat(const double* __restrict__ part, const float* __restrict__ bias,
                        const float* __restrict__ g, const float* __restrict__ bsh,
                        float2* __restrict__ ss, int O){
  int o = threadIdx.x;
  if (o >= O) return;
  double S = 0.0, P = 0.0;
  for (int b = 0; b < 2; ++b)
    for (int zb = 0; zb < 16; ++zb){
      size_t base = ((size_t)(b*O + o)*16 + zb)*2;
      S += part[base]; P += part[base+1];
    }
  P *= (1.0/4096.0);
  double N = 524288.0;
  double bi = bias[o];
  double mean = S/N + bi;
  double var = P/N + 2.0*bi*S/N + bi*bi - mean*mean;
  double sc = (double)g[o] / sqrt(var + 1e-5);
  ss[o] = make_float2((float)sc, (float)((bi - mean)*sc + (double)bsh[o]));
}

// ---------------- fused ifft2 + BN + ReLU + mean over gamma ----------------
__global__ __launch_bounds__(TPB) void k_final(const float2* __restrict__ Xt, const float2* __restrict__ ss,
                                               float* __restrict__ out, int O){
  __shared__ float2 W[64];
  __shared__ __attribute__((aligned(16))) float2 buf[64*65];
  __shared__ float s4[4*64];
  int bo = blockIdx.x >> 6;
  int o = bo % O;
  init_W(W, 1.f);
  int tid = threadIdx.x, lane = tid & 63, wid = tid >> 6;
  int rl = (int)(__brev((uintT)lane) >> 26);
  const float2* src = Xt + (size_t)blockIdx.x*2016;
  build_plane_c(src, buf);
  __syncthreads();
  #pragma unroll 4
  for (int i = 0; i < 16; ++i){
    int r = wid*16 + i;
    float2 x = buf[r*65 + lane];
    x = fft64_lane(x, W, lane);
    buf[r*65 + rl] = x;
  }
  __syncthreads();
  float2 sv = ss[o];
  float acc = 0.f;
  #pragma unroll 4
  for (int i = 0; i < 16; ++i){
    int c = wid*16 + i;
    float2 x = buf[lane*65 + c];
    x = fft64_lane(x, W, lane);
    acc += fmaxf(fmaf(x.x*(1.f/4096.f), sv.x, sv.y), 0.f);
  }
  s4[wid*64 + rl] = acc;
  __syncthreads();
  if (tid < 64)
    out[(size_t)blockIdx.x*64 + tid] = (s4[tid] + s4[64+tid] + s4[128+tid] + s4[192+tid]) * (1.f/64.f);
}

extern "C" void kernel_launch(void* const* d_in, const int* in_sizes, int n_in,
                              void* d_out, int out_size, void* d_ws, size_t ws_size,
                              hipStream_t stream){
  const float* x   = (const float*)d_in[0];
  const float* ks2 = (const float*)d_in[1];
  const float* bs2 = (const float*)d_in[2];
  const float* k1  = (const float*)d_in[3];
  const float* b1c = (const float*)d_in[4];
  const float* k2  = (const float*)d_in[5];
  const float* b2c = (const float*)d_in[6];
  const float* k3  = (const float*)d_in[7];
  const float* b3c = (const float*)d_in[8];
  const float* g1 = (const float*)d_in[9],  *bb1 = (const float*)d_in[10];
  const float* g2 = (const float*)d_in[11], *bb2 = (const float*)d_in[12];
  const float* g3 = (const float*)d_in[13], *bb3 = (const float*)d_in[14];
  const float* g4 = (const float*)d_in[15], *bb4 = (const float*)d_in[16];
  float* out = (float*)d_out;

  char* w = (char*)d_ws;
  size_t off = 0;
  auto take = [&](size_t bytes)->char*{
    char* p = w + off;
    off += (bytes + 255) & ~(size_t)255;
    return p;
  };
  float*  Dz   = (float*) take(64ull*32*32*63*4);
  float*  Deq  = (float*) take(32ull*63*63*4);
  double* lf   = (double*)take(65*8);
  double* qw   = (double*)take(64*8);
  double* part = (double*)take(75ull*64*2*8);
  float2* ss   = (float2*)take(75*8);
  float2* KhS2 = (float2*)take(63ull*25*3*8);
  float2* Kh1  = (float2*)take(63ull*25*25*8);
  float2* Kh2  = (float2*)take(63ull*25*50*8);
  float2* Kh3  = (float2*)take(63ull*36*75*8);
  float2* XH2  = (float2*)take(2ull*3*64*63*8);
  float2* F2   = (float2*)take(2ull*3*32*63*8);
  ushortT* X1  = (ushortT*)take(2ull*25*262144*2);
  ushortT* X2  = (ushortT*)take(2ull*25*262144*2);
  ushortT* X3  = (ushortT*)take(2ull*25*262144*2);
  float2* A    = (float2*)take(150ull*32*2016*8);
  float2* B    = (float2*)take(150ull*32*2016*8);
  if (off > ws_size) return;

  dim3 tpb(TPB);
  auto cdiv = [](long long a, long long b){ return (int)((a + b - 1) / b); };

  k_tables<<<1, 64, 0, stream>>>(lf, qw);
  k_wigner<<<dim3(65,32), tpb, 0, stream>>>(lf, Dz, Deq);
  k_kh<<<cdiv(3ll*25*63,TPB),  tpb, 0, stream>>>(ks2, KhS2, 3, 25,  (float)(1.0/sqrt(196608.0)));
  k_kh<<<cdiv(25ll*25*63,TPB), tpb, 0, stream>>>(k1,  Kh1, 25, 25, (float)(1.0/sqrt(1600.0)));
  k_kh<<<cdiv(50ll*25*63,TPB), tpb, 0, stream>>>(k2,  Kh2, 50, 25, (float)(1.0/sqrt(3200.0)));
  k_kh<<<cdiv(75ll*36*63,TPB), tpb, 0, stream>>>(k3,  Kh3, 75, 36, (float)(1.0/sqrt(4800.0)));

  // ---- S2 conv ----
  k_s2_fft<<<cdiv(2ll*3*64*63,TPB), tpb, 0, stream>>>(x, XH2);
  k_s2_F<<<cdiv(2ll*3*32*63,TPB), tpb, 0, stream>>>(Dz, qw, XH2, F2);
  k_s2_zhat<<<cdiv(2ll*25*32*2016,TPB), tpb, 0, stream>>>(Deq, F2, KhS2, B);
  {
    int nchB = (50 + 7) >> 3, zbB = (nchB + 3)/4;
    k_wig_synth<<<dim3(32,8,2*zbB), tpb, 0, stream>>>(Dz, B, A, 50, nchB);
  }
  k_ifft2_sym<<<50*64, tpb, 0, stream>>>(A, X1, bs2, 25);

  // ---- generic SO3 conv ----
  auto so3 = [&](const ushortT* Xa, const ushortT* Xb, const ushortT* Xc, int Cin,
                 const float* g, const float* bb, const float2* Kh, int O,
                 const float* bias, ushortT* Xout, int isFinal){
    int BC = 2*Cin, BO = 2*O;
    k_bnstats<<<dim3(25,64), tpb, 0, stream>>>(Xa, 0, part);
    if (Cin > 25) k_bnstats<<<dim3(25,64), tpb, 0, stream>>>(Xb, 25, part);
    if (Cin > 50) k_bnstats<<<dim3(25,64), tpb, 0, stream>>>(Xc, 50, part);
    k_bnfinal<<<1, 128, 0, stream>>>(part, g, bb, ss, Cin);
    int nch = (BC + 7) >> 3, zb = (nch + 3)/4;
    for (int z0 = 0; z0 < 64; z0 += 32){
      k_fft2_fwd<<<dim3(BC,32), tpb, 0, stream>>>(Xa, Xb, Xc, ss, A, Cin, z0);
      k_wig_F<<<dim3(32,8,zb), tpb, 0, stream>>>(Dz, qw, A, B, BC, z0, z0 > 0 ? 1 : 0, nch);
    }
    k_deq_C<<<dim3(32,32), tpb, 0, stream>>>(Deq, B, A, BC);
    k_kh_z<<<dim3(63,2,8), tpb, 0, stream>>>(A, Kh, B, Cin, O);
    int nchB = (BO + 7) >> 3, zbB = (nchB + 3)/4;
    k_wig_synth<<<dim3(32,8,2*zbB), tpb, 0, stream>>>(Dz, B, A, BO, nchB);
    if (!isFinal){
      k_ifft2_sym<<<BO*64, tpb, 0, stream>>>(A, Xout, bias, O);
    } else {
      k_stats3<<<dim3(BO,16), tpb, 0, stream>>>(A, part);
      k_fstat<<<1, 64, 0, stream>>>(part, bias, g4, bb4, ss, O);
      k_final<<<BO*64, tpb, 0, stream>>>(A, ss, out, O);
    }
  };

  so3(X1, X1, X1, 25, g1, bb1, Kh1, 25, b1c, X2, 0);
  so3(X1, X2, X2, 50, g2, bb2, Kh2, 25, b2c, X3, 0);
  so3(X1, X2, X3, 75, g3, bb3, Kh3, 36, b3c, nullptr, 1);
}

// Round 4
// 2457.151 us; speedup vs baseline: 2.0848x; 1.5063x over previous
//
#include <hip/hip_runtime.h>
#include <math.h>

#define PI_D 3.14159265358979323846
#define TPB 256
typedef unsigned short ushortT;
typedef unsigned int uintT;

__device__ __forceinline__ float2 cxmul(float2 a, float2 b){
  return make_float2(a.x*b.x - a.y*b.y, a.x*b.y + a.y*b.x);
}
__device__ __forceinline__ float bf2f(ushortT u){
  uintT x = ((uintT)u) << 16;
  return __uint_as_float(x);
}
__device__ __forceinline__ ushortT f2bf(float f){
  uintT x = __float_as_uint(f);
  x = x + 0x7FFFu + ((x >> 16) & 1u);
  return (ushortT)(x >> 16);
}

// ---------------- tables ----------------
__global__ void k_tables(double* lf, double* qw){
  if (threadIdx.x == 0){
    lf[0] = 0.0;
    for (int i = 1; i <= 64; ++i) lf[i] = lf[i-1] + log((double)i);
  }
  int j = threadIdx.x;
  if (j < 64){
    double s1 = sin(PI_D*(2*j+1)/128.0);
    double inner = 0.0;
    for (int k = 0; k < 32; ++k)
      inner += (1.0/(double)(2*k+1)) * sin((double)(2*j+1)*(double)(2*k+1)*PI_D/128.0);
    qw[j] = (2.0/32.0) * s1 * inner;
  }
}

__device__ double wigd(const double* lfs, int l, int mp, int m, double lc, double ls){
  if (mp < -l || mp > l || m < -l || m > l) return 0.0;
  int k0 = (m - mp > 0) ? (m - mp) : 0;
  int k1 = (l + m < l - mp) ? (l + m) : (l - mp);
  double base = 0.5*(lfs[l+mp] + lfs[l-mp] + lfs[l+m] + lfs[l-m]);
  double val = 0.0;
  for (int k = k0; k <= k1; ++k){
    double t = base - lfs[l+m-k] - lfs[k] - lfs[mp-m+k] - lfs[l-mp-k]
             + (double)(2*l + m - mp - 2*k)*lc + (double)(mp - m + 2*k)*ls;
    double e = exp(t);
    val += ((mp - m + k) & 1) ? -e : e;
  }
  return val;
}

// Dz[z][l][mi'][n], Deq[l][r][c]
__global__ __launch_bounds__(TPB) void k_wigner(const double* __restrict__ lf,
                                                float* __restrict__ Dz, float* __restrict__ Deq){
  __shared__ double lfs[65];
  if (threadIdx.x < 65) lfs[threadIdx.x] = lf[threadIdx.x];
  __syncthreads();
  int zs = blockIdx.x, l = blockIdx.y;
  double beta = (zs < 64) ? ((double)zs + 0.5)*PI_D/64.0 : PI_D*0.5;
  double ch = cos(beta*0.5), sh = sin(beta*0.5);
  double lc = log(ch), ls = log(sh);
  if (zs < 64){
    for (int idx = threadIdx.x; idx < 2016; idx += TPB){
      int mi = idx/63, c = idx%63;
      Dz[((size_t)(zs*32 + l)*32 + mi)*63 + c] = (float)wigd(lfs, l, mi, c-31, lc, ls);
    }
  } else {
    for (int idx = threadIdx.x; idx < 3969; idx += TPB){
      int r = idx/63, c = idx%63;
      Deq[((size_t)l*63 + r)*63 + c] = (float)wigd(lfs, l, r-31, c-31, lc, ls);
    }
  }
}

// Kh[o][i][n] = scale * sum_p K[i,o,p] * exp(-i*2pi*p*(n-31)/64)
__global__ void k_kh(const float* __restrict__ K, float2* __restrict__ Kh, int I, int O, float scale){
  int idx = blockIdx.x*blockDim.x + threadIdx.x;
  if (idx >= I*O*63) return;
  int n = idx % 63, i = (idx/63) % I, o = idx/(63*I);
  float sr = 0.f, si = 0.f;
  for (int p = 0; p < 64; ++p){
    int t = (p * (n - 31)) & 63;
    float s, c;
    sincosf(-(float)PI_D/32.f * (float)t, &s, &c);
    float kv = K[(i*O + o)*64 + p];
    sr += kv * c; si += kv * s;
  }
  Kh[((size_t)o*I + i)*63 + n] = make_float2(sr*scale, si*scale);
}

// ---------------- S2 front ----------------
__global__ void k_s2_fft(const float* __restrict__ x, float2* __restrict__ XH2){
  int idx = blockIdx.x*blockDim.x + threadIdx.x;
  if (idx >= 2*3*64*63) return;
  int mi = idx % 63; int z = (idx/63) & 63; int bc = idx / (63*64);
  int f = (mi + 33) & 63;
  const float* row = x + ((size_t)bc*64 + z)*64;
  float sr = 0.f, si = 0.f;
  for (int a = 0; a < 64; ++a){
    int t = (f*a) & 63;
    float s, c;
    sincosf(-(float)PI_D/32.f * (float)t, &s, &c);
    sr += row[a]*c; si += row[a]*s;
  }
  XH2[idx] = make_float2(sr, si);
}

__global__ void k_s2_F(const float* __restrict__ Dz, const double* __restrict__ qw,
                       const float2* __restrict__ XH2, float2* __restrict__ F2){
  int idx = blockIdx.x*blockDim.x + threadIdx.x;
  if (idx >= 2*3*32*63) return;
  int r = idx % 63; int l = (idx/63) & 31; int bc = idx / (63*32);
  float2 acc = make_float2(0,0);
  for (int z = 0; z < 64; ++z){
    float d;
    if (r >= 31) d = Dz[((size_t)(z*32 + l)*32 + (r-31))*63 + 31];
    else {
      d = Dz[((size_t)(z*32 + l)*32 + (31-r))*63 + 31];
      if ((31-r) & 1) d = -d;
    }
    float wv = (float)qw[z] * d;
    float2 v = XH2[((size_t)bc*64 + z)*63 + r];
    acc.x += wv*v.x; acc.y += wv*v.y;
  }
  F2[idx] = acc;
}

__global__ void k_s2_zhat(const float* __restrict__ Deq, const float2* __restrict__ F2,
                          const float2* __restrict__ Kh, float2* __restrict__ Z){
  int idx = blockIdx.x*blockDim.x + threadIdx.x;
  if (idx >= 2*25*32*2016) return;
  int n = idx % 63; int mi = (idx/63) & 31; int l = (idx/2016) & 31;
  int o = (idx/(2016*32)) % 25; int b = idx/(2016*32*25);
  float deq0 = Deq[((size_t)l*63 + n)*63 + 31];
  float2 acc = make_float2(0,0);
  for (int i = 0; i < 3; ++i){
    float2 f = F2[((size_t)(b*3 + i)*32 + l)*63 + (mi+31)];
    float2 kh = Kh[((size_t)(o*3 + i))*63 + n];
    float2 p = cxmul(f, kh);
    acc.x += p.x; acc.y += p.y;
  }
  Z[((size_t)((b*25+o)*32) + l)*2016 + mi*63 + n] = make_float2(acc.x*deq0, acc.y*deq0);
}

// ---------------- BN stats over bf16 X buffers ----------------
__global__ __launch_bounds__(TPB) void k_bnstats(const ushortT* __restrict__ src, int slotBase,
                                                 double* __restrict__ part){
  int c = blockIdx.x, blk = blockIdx.y;
  const uint2* s4 = (const uint2*)src;
  double s = 0.0, q = 0.0;
  for (int k = 0; k < 8; ++k){
    int g4 = blk*2048 + k*256 + threadIdx.x;
    int b = g4 >> 16, pos4 = g4 & 65535;
    uint2 u = s4[((size_t)(b*25 + c))*65536 + pos4];
    float v0 = bf2f((ushortT)(u.x & 0xffff)), v1 = bf2f((ushortT)(u.x >> 16));
    float v2 = bf2f((ushortT)(u.y & 0xffff)), v3 = bf2f((ushortT)(u.y >> 16));
    s += (double)v0 + v1 + v2 + v3;
    q += (double)v0*v0 + (double)v1*v1 + (double)v2*v2 + (double)v3*v3;
  }
  __shared__ double sh[TPB], sh2[TPB];
  sh[threadIdx.x] = s; sh2[threadIdx.x] = q;
  __syncthreads();
  for (int o = 128; o > 0; o >>= 1){
    if (threadIdx.x < o){ sh[threadIdx.x] += sh[threadIdx.x+o]; sh2[threadIdx.x] += sh2[threadIdx.x+o]; }
    __syncthreads();
  }
  if (threadIdx.x == 0){
    part[((size_t)(slotBase + c)*64 + blk)*2 + 0] = sh[0];
    part[((size_t)(slotBase + c)*64 + blk)*2 + 1] = sh2[0];
  }
}

__global__ void k_bnfinal(const double* __restrict__ part, const float* __restrict__ g,
                          const float* __restrict__ b, float2* __restrict__ ss, int C){
  int c = blockIdx.x*blockDim.x + threadIdx.x;
  if (c >= C) return;
  double s = 0.0, q = 0.0;
  for (int k = 0; k < 64; ++k){
    s += part[((size_t)c*64 + k)*2 + 0];
    q += part[((size_t)c*64 + k)*2 + 1];
  }
  double N = 524288.0;
  double mu = s / N;
  double var = q / N - mu*mu;
  double sc = (double)g[c] / sqrt(var + 1e-5);
  ss[c] = make_float2((float)sc, (float)((double)b[c] - mu*sc));
}

// ---------------- 64-pt FFT across lanes (radix-2 DIF, shfl) ----------------
__device__ __forceinline__ float2 fft64_lane(float2 x, const float2* __restrict__ Wt, int lane){
  #pragma unroll
  for (int st = 0; st < 6; ++st){
    int h = 32 >> st;
    float2 p;
    p.x = __shfl_xor(x.x, h, 64);
    p.y = __shfl_xor(x.y, h, 64);
    if (lane & h){
      float2 s = make_float2(p.x - x.x, p.y - x.y);
      x = cxmul(s, Wt[(lane & (h-1)) << st]);
    } else {
      x = make_float2(x.x + p.x, x.y + p.y);
    }
  }
  return x;
}
__device__ __forceinline__ void init_W(float2* W, float sign){
  if (threadIdx.x < 64){
    float s, c;
    sincosf(sign*(float)(2.0*PI_D/64.0)*(float)threadIdx.x, &s, &c);
    W[threadIdx.x] = make_float2(c, s);
  }
}

// ---------------- fused BN+ReLU + fft2 + reduced centered extraction ----------------
__global__ __launch_bounds__(TPB) void k_fft2_fwd(const ushortT* __restrict__ X1, const ushortT* __restrict__ X2,
                                                  const ushortT* __restrict__ X3, const float2* __restrict__ ss,
                                                  float2* __restrict__ XH, int Cin, int z0){
  __shared__ float2 W[64];
  __shared__ __attribute__((aligned(16))) float2 buf[64*65];
  int bc = blockIdx.x, zz = blockIdx.y, z = z0 + zz;
  int b = bc / Cin, ci = bc % Cin;
  const ushortT* src; int cl;
  if (ci < 25){ src = X1; cl = ci; }
  else if (ci < 50){ src = X2; cl = ci - 25; }
  else { src = X3; cl = ci - 50; }
  src += ((size_t)(b*25 + cl)*64 + z)*4096;
  float2 sc = ss[ci];
  init_W(W, -1.f);
  int tid = threadIdx.x, lane = tid & 63, wid = tid >> 6;
  int rl = (int)(__brev((uintT)lane) >> 26);
  const uintT* s32 = (const uintT*)src;
  for (int i = tid; i < 2048; i += TPB){
    uintT u = s32[i];
    float v0 = fmaxf(bf2f((ushortT)(u & 0xffff))*sc.x + sc.y, 0.f);
    float v1 = fmaxf(bf2f((ushortT)(u >> 16))*sc.x + sc.y, 0.f);
    int row = i >> 5, col = (i << 1) & 63;
    buf[row*65 + col]     = make_float2(v0, 0.f);
    buf[row*65 + col + 1] = make_float2(v1, 0.f);
  }
  __syncthreads();
  #pragma unroll 4
  for (int i = 0; i < 16; ++i){
    int r = wid*16 + i;
    float2 x = buf[r*65 + lane];
    x = fft64_lane(x, W, lane);
    buf[r*65 + rl] = x;
  }
  __syncthreads();
  #pragma unroll 4
  for (int i = 0; i < 16; ++i){
    int c = wid*16 + i;
    float2 x = buf[lane*65 + c];
    x = fft64_lane(x, W, lane);
    buf[rl*65 + c] = x;
  }
  __syncthreads();
  float2* dst = XH + ((size_t)bc*32 + zz)*2016;
  for (int idx = tid; idx < 2016; idx += TPB){
    int mi = idx / 63, n = idx % 63;
    dst[idx] = buf[mi*65 + ((n+33)&63)];
  }
}

// ---------------- F[bc,l,mi,n] (+)= sum_z qw*Dz*XH — register-tiled ----------------
// grid (32 mi, 8 nt, ceil(BC/16)); block 256
__global__ __launch_bounds__(TPB) void k_wig_F(const float* __restrict__ Dz, const double* __restrict__ qw,
                                               const float2* __restrict__ XH, float2* __restrict__ F,
                                               int BC, int z0, int accum){
  __shared__ __attribute__((aligned(16))) float sm[9088];
  float* Dt = sm;                          // [z16][nn8][l 36pad]
  float2* Xt = (float2*)(sm + 4608);       // [bc16][130]
  int mi = blockIdx.x, nt = blockIdx.y, bcBase = blockIdx.z*16;
  int tid = threadIdx.x;
  int bg = tid & 3, lg = (tid>>2)&7, ng = tid>>5;
  float2 acc[4][4];
  #pragma unroll
  for (int a = 0; a < 4; ++a)
    #pragma unroll
    for (int j = 0; j < 4; ++j) acc[a][j] = make_float2(0,0);
  for (int zq = 0; zq < 32; zq += 16){
    __syncthreads();
    for (int idx = tid; idx < 4096; idx += TPB){
      int z = idx >> 8, l = (idx>>3)&31, nn = idx&7;
      int n = nt*8 + nn;
      float v = 0.f;
      if (n < 63) v = Dz[(((size_t)(z0+zq+z)*32 + l)*32 + mi)*63 + n] * (float)qw[z0+zq+z];
      Dt[(z*8+nn)*36 + l] = v;
    }
    for (int idx = tid; idx < 2048; idx += TPB){
      int bc = idx >> 7, z = (idx>>3)&15, nn = idx&7;
      int gbc = bcBase + bc, n = nt*8 + nn;
      float2 v = make_float2(0,0);
      if (gbc < BC && n < 63) v = XH[((size_t)gbc*32 + zq + z)*2016 + mi*63 + n];
      Xt[bc*130 + z*8 + nn] = v;
    }
    __syncthreads();
    #pragma unroll 4
    for (int z = 0; z < 16; ++z){
      const float4 d = *(const float4*)&Dt[(z*8+ng)*36 + lg*4];
      float dd[4] = {d.x, d.y, d.z, d.w};
      float2 xv[4];
      #pragma unroll
      for (int j = 0; j < 4; ++j) xv[j] = Xt[(bg + 4*j)*130 + z*8 + ng];
      #pragma unroll
      for (int j = 0; j < 4; ++j)
        #pragma unroll
        for (int dl = 0; dl < 4; ++dl){
          acc[j][dl].x += dd[dl]*xv[j].x;
          acc[j][dl].y += dd[dl]*xv[j].y;
        }
    }
  }
  __syncthreads();
  float2* St = (float2*)sm;                // [bc16][l32][nn8]
  #pragma unroll
  for (int j = 0; j < 4; ++j)
    #pragma unroll
    for (int dl = 0; dl < 4; ++dl)
      St[(((bg + 4*j)*32) + lg*4 + dl)*8 + ng] = acc[j][dl];
  __syncthreads();
  for (int idx = tid; idx < 4096; idx += TPB){
    int bc = idx >> 8, l = (idx>>3)&31, nn = idx&7;
    int gbc = bcBase + bc, n = nt*8 + nn;
    if (gbc < BC && n < 63){
      size_t a = ((size_t)(gbc*32 + l))*2016 + mi*63 + n;
      float2 v = St[idx];
      if (accum){ float2 o = F[a]; v.x += o.x; v.y += o.y; }
      F[a] = v;
    }
  }
}

// ---------------- C[bi,l,mi,n] = sum_k F[bi,l,mi,k]*Deq[l,n,k] — register-tiled ----------------
// grid (32 l, 32 mi, ceil(BC/64)); block 256
__global__ __launch_bounds__(TPB) void k_deq_C(const float* __restrict__ Deq, const float2* __restrict__ F,
                                               float2* __restrict__ C, int BC){
  __shared__ __attribute__((aligned(16))) float sm[12604];
  float2* Fb = (float2*)sm;                // [bi64][65pad]
  float* DeqT = sm + 8320;                 // [k63][68pad n]
  int l = blockIdx.x, mi = blockIdx.y, biBase = blockIdx.z*64;
  int tid = threadIdx.x;
  int ngr = tid & 15, big = tid >> 4;
  for (int idx = tid; idx < 3969; idx += TPB){
    int n = idx/63, k = idx - n*63;
    DeqT[k*68 + n] = Deq[((size_t)l*63 + n)*63 + k];
  }
  for (int idx = tid; idx < 4032; idx += TPB){
    int bi = idx/63, k = idx - bi*63;
    int gbi = biBase + bi;
    Fb[bi*65 + k] = (gbi < BC) ? F[((size_t)(gbi*32 + l))*2016 + mi*63 + k] : make_float2(0,0);
  }
  __syncthreads();
  float2 acc[4][4];
  #pragma unroll
  for (int a = 0; a < 4; ++a)
    #pragma unroll
    for (int j = 0; j < 4; ++j) acc[a][j] = make_float2(0,0);
  #pragma unroll 3
  for (int k = 0; k < 63; ++k){
    const float4 d = *(const float4*)&DeqT[k*68 + ngr*4];
    float dd[4] = {d.x, d.y, d.z, d.w};
    float2 fv[4];
    #pragma unroll
    for (int j = 0; j < 4; ++j) fv[j] = Fb[(big + 16*j)*65 + k];
    #pragma unroll
    for (int j = 0; j < 4; ++j)
      #pragma unroll
      for (int dn = 0; dn < 4; ++dn){
        acc[j][dn].x += dd[dn]*fv[j].x;
        acc[j][dn].y += dd[dn]*fv[j].y;
      }
  }
  __syncthreads();
  float2* St = (float2*)sm;                // [bi64][n63]
  #pragma unroll
  for (int j = 0; j < 4; ++j)
    #pragma unroll
    for (int dn = 0; dn < 4; ++dn){
      int n = ngr*4 + dn;
      if (n < 63) St[(big + 16*j)*63 + n] = acc[j][dn];
    }
  __syncthreads();
  for (int idx = tid; idx < 4032; idx += TPB){
    int bi = idx/63, n = idx - bi*63;
    int gbi = biBase + bi;
    if (gbi < BC) C[((size_t)(gbi*32 + l))*2016 + mi*63 + n] = St[idx];
  }
}

// ---------------- Z[b,o,l,mi,n] = sum_i Kh[o,i,n]*C[b,i,l,mi,n] ----------------
// grid (32 l, 32 mi); block 256 (252 active for compute)
__global__ __launch_bounds__(TPB) void k_kh_z(const float2* __restrict__ C, const float2* __restrict__ Kh,
                                              float2* __restrict__ Z, int I, int O){
  __shared__ float2 Ct[150*22];            // [b*I+i][nn 22pad]
  int l = blockIdx.x, mi = blockIdx.y;
  int tid = threadIdx.x;
  int nn = tid % 21, og = tid / 21;        // og 0..12
  int rows = 2*I;
  for (int nc = 0; nc < 3; ++nc){
    int n0 = nc*21;
    __syncthreads();
    for (int idx = tid; idx < rows*21; idx += TPB){
      int row = idx/21, k = idx - row*21;
      Ct[row*22 + k] = C[((size_t)(row*32 + l))*2016 + mi*63 + n0 + k];
    }
    __syncthreads();
    if (og < 12){
      float2 acc[3][2];
      #pragma unroll
      for (int r = 0; r < 3; ++r){ acc[r][0] = make_float2(0,0); acc[r][1] = make_float2(0,0); }
      for (int i = 0; i < I; ++i){
        float2 c0 = Ct[i*22 + nn];
        float2 c1 = Ct[(I + i)*22 + nn];
        #pragma unroll
        for (int r = 0; r < 3; ++r){
          int o = og + r*12;
          if (o < O){
            float2 kh = Kh[((size_t)(o*I + i))*63 + n0 + nn];
            acc[r][0].x += kh.x*c0.x - kh.y*c0.y;
            acc[r][0].y += kh.x*c0.y + kh.y*c0.x;
            acc[r][1].x += kh.x*c1.x - kh.y*c1.y;
            acc[r][1].y += kh.x*c1.y + kh.y*c1.x;
          }
        }
      }
      #pragma unroll
      for (int r = 0; r < 3; ++r){
        int o = og + r*12;
        if (o < O){
          Z[((size_t)((0*O + o)*32 + l))*2016 + mi*63 + n0 + nn] = acc[r][0];
          Z[((size_t)((1*O + o)*32 + l))*2016 + mi*63 + n0 + nn] = acc[r][1];
        }
      }
    }
  }
}

// ---------------- Xt[bo,z,mi,n] = sum_l wl*Dz*Z — register-tiled ----------------
// grid (32 mi, 8 nt, 2*ceil(BO/16)); block 256
__global__ __launch_bounds__(TPB) void k_wig_synth(const float* __restrict__ Dz, const float2* __restrict__ Z,
                                                   float2* __restrict__ Xt_g, int BO){
  __shared__ __attribute__((aligned(16))) float sm[9088];
  float* Dt = sm;                          // [l16][nn8][z 36pad]
  float2* Zt = (float2*)(sm + 4608);       // [bo16][130]
  int mi = blockIdx.x, nt = blockIdx.y;
  int z0 = (blockIdx.z & 1)*32;
  int boBase = (blockIdx.z >> 1)*16;
  int tid = threadIdx.x;
  int bg = tid & 3, zg = (tid>>2)&7, ng = tid>>5;
  float2 acc[4][4];
  #pragma unroll
  for (int a = 0; a < 4; ++a)
    #pragma unroll
    for (int j = 0; j < 4; ++j) acc[a][j] = make_float2(0,0);
  for (int lq = 0; lq < 32; lq += 16){
    __syncthreads();
    for (int idx = tid; idx < 4096; idx += TPB){
      int ll = idx >> 8, z = (idx>>3)&31, nn = idx&7;
      int n = nt*8 + nn, lG = lq + ll;
      float v = 0.f;
      if (n < 63) v = Dz[(((size_t)(z0+z)*32 + lG)*32 + mi)*63 + n] * (0.5f*(float)(2*lG+1));
      Dt[(ll*8+nn)*36 + z] = v;
    }
    for (int idx = tid; idx < 2048; idx += TPB){
      int bo = idx >> 7, ll = (idx>>3)&15, nn = idx&7;
      int gbo = boBase + bo, n = nt*8 + nn;
      float2 v = make_float2(0,0);
      if (gbo < BO && n < 63) v = Z[((size_t)(gbo*32 + lq + ll))*2016 + mi*63 + n];
      Zt[bo*130 + ll*8 + nn] = v;
    }
    __syncthreads();
    #pragma unroll 4
    for (int ll = 0; ll < 16; ++ll){
      const float4 d = *(const float4*)&Dt[(ll*8+ng)*36 + zg*4];
      float dd[4] = {d.x, d.y, d.z, d.w};
      float2 zv[4];
      #pragma unroll
      for (int j = 0; j < 4; ++j) zv[j] = Zt[(bg + 4*j)*130 + ll*8 + ng];
      #pragma unroll
      for (int j = 0; j < 4; ++j)
        #pragma unroll
        for (int dz = 0; dz < 4; ++dz){
          acc[j][dz].x += dd[dz]*zv[j].x;
          acc[j][dz].y += dd[dz]*zv[j].y;
        }
    }
  }
  __syncthreads();
  float2* St = (float2*)sm;                // [bo16][z32][nn8]
  #pragma unroll
  for (int j = 0; j < 4; ++j)
    #pragma unroll
    for (int dz = 0; dz < 4; ++dz)
      St[(((bg + 4*j)*32) + zg*4 + dz)*8 + ng] = acc[j][dz];
  __syncthreads();
  for (int idx = tid; idx < 4096; idx += TPB){
    int bo = idx >> 8, z = (idx>>3)&31, nn = idx&7;
    int gbo = boBase + bo, n = nt*8 + nn;
    if (gbo < BO && n < 63)
      Xt_g[((size_t)gbo*64 + z0 + z)*2016 + mi*63 + n] = St[idx];
  }
}

// ---------------- coalesced Hermitian build ----------------
__device__ __forceinline__ void build_plane_c(const float2* __restrict__ src, float2* buf){
  int tid = threadIdx.x;
  if (tid < 128){
    int k = tid & 63;
    if (tid < 64) buf[32*65 + k] = make_float2(0,0);
    else          buf[k*65 + 32] = make_float2(0,0);
  }
  for (int idx = tid; idx < 2016; idx += TPB){
    float2 v = src[idx];
    int mi = idx / 63, ni = idx - mi*63;
    buf[mi*65 + ((ni+33)&63)] = v;
    if (mi > 0) buf[(64-mi)*65 + ((31-ni)&63)] = make_float2(v.x, -v.y);
  }
}

// ---------------- ifft2 + real + bias -> bf16 X ----------------
__global__ __launch_bounds__(TPB) void k_ifft2_sym(const float2* __restrict__ Xt, ushortT* __restrict__ Xo,
                                                   const float* __restrict__ bias, int O){
  __shared__ float2 W[64];
  __shared__ __attribute__((aligned(16))) float2 buf[64*65];
  int bo = blockIdx.x >> 6;
  int o = bo % O;
  init_W(W, 1.f);
  int tid = threadIdx.x, lane = tid & 63, wid = tid >> 6;
  int rl = (int)(__brev((uintT)lane) >> 26);
  const float2* src = Xt + (size_t)blockIdx.x*2016;
  build_plane_c(src, buf);
  __syncthreads();
  #pragma unroll 4
  for (int i = 0; i < 16; ++i){
    int r = wid*16 + i;
    float2 x = buf[r*65 + lane];
    x = fft64_lane(x, W, lane);
    buf[r*65 + rl] = x;
  }
  __syncthreads();
  #pragma unroll 4
  for (int i = 0; i < 16; ++i){
    int c = wid*16 + i;
    float2 x = buf[lane*65 + c];
    x = fft64_lane(x, W, lane);
    buf[rl*65 + c] = x;
  }
  __syncthreads();
  float bb = bias[o];
  ushortT* dst = Xo + (size_t)blockIdx.x*4096;
  for (int idx = tid; idx < 4096; idx += TPB){
    dst[idx] = f2bf(buf[(idx>>6)*65 + (idx&63)].x * (1.f/4096.f) + bb);
  }
}

// ---------------- conv3 final stats from spectrum (Parseval) ----------------
__global__ __launch_bounds__(TPB) void k_stats3(const float2* __restrict__ Xt, double* __restrict__ part){
  int bo = blockIdx.x, zb = blockIdx.y;
  double s = 0.0, p = 0.0;
  for (int zz = 0; zz < 4; ++zz){
    const float2* pl = Xt + ((size_t)bo*64 + zb*4 + zz)*2016;
    for (int idx = threadIdx.x; idx < 2016; idx += TPB){
      float2 v = pl[idx];
      double q = (double)v.x*v.x + (double)v.y*v.y;
      p += (idx < 63) ? q : 2.0*q;
      if (idx == 31) s += v.x;
    }
  }
  __shared__ double sh[TPB], sh2[TPB];
  sh[threadIdx.x] = s; sh2[threadIdx.x] = p;
  __syncthreads();
  for (int o = 128; o > 0; o >>= 1){
    if (threadIdx.x < o){ sh[threadIdx.x] += sh[threadIdx.x+o]; sh2[threadIdx.x] += sh2[threadIdx.x+o]; }
    __syncthreads();
  }
  if (threadIdx.x == 0){
    part[((size_t)bo*16 + zb)*2 + 0] = sh[0];
    part[((size_t)bo*16 + zb)*2 + 1] = sh2[0];
  }
}

__global__ void k_fstat(const double* __restrict__ part, const float* __restrict__ bias,
                        const float* __restrict__ g, const float* __restrict__ bsh,
                        float2* __restrict__ ss, int O){
  int o = threadIdx.x;
  if (o >= O) return;
  double S = 0.0, P = 0.0;
  for (int b = 0; b < 2; ++b)
    for (int zb = 0; zb < 16; ++zb){
      size_t base = ((size_t)(b*O + o)*16 + zb)*2;
      S += part[base]; P += part[base+1];
    }
  P *= (1.0/4096.0);
  double N = 524288.0;
  double bi = bias[o];
  double mean = S/N + bi;
  double var = P/N + 2.0*bi*S/N + bi*bi - mean*mean;
  double sc = (double)g[o] / sqrt(var + 1e-5);
  ss[o] = make_float2((float)sc, (float)((bi - mean)*sc + (double)bsh[o]));
}

// ---------------- fused ifft2 + BN + ReLU + mean over gamma ----------------
__global__ __launch_bounds__(TPB) void k_final(const float2* __restrict__ Xt, const float2* __restrict__ ss,
                                               float* __restrict__ out, int O){
  __shared__ float2 W[64];
  __shared__ __attribute__((aligned(16))) float2 buf[64*65];
  __shared__ float s4[4*64];
  int bo = blockIdx.x >> 6;
  int o = bo % O;
  init_W(W, 1.f);
  int tid = threadIdx.x, lane = tid & 63, wid = tid >> 6;
  int rl = (int)(__brev((uintT)lane) >> 26);
  const float2* src = Xt + (size_t)blockIdx.x*2016;
  build_plane_c(src, buf);
  __syncthreads();
  #pragma unroll 4
  for (int i = 0; i < 16; ++i){
    int r = wid*16 + i;
    float2 x = buf[r*65 + lane];
    x = fft64_lane(x, W, lane);
    buf[r*65 + rl] = x;
  }
  __syncthreads();
  float2 sv = ss[o];
  float acc = 0.f;
  #pragma unroll 4
  for (int i = 0; i < 16; ++i){
    int c = wid*16 + i;
    float2 x = buf[lane*65 + c];
    x = fft64_lane(x, W, lane);
    acc += fmaxf(fmaf(x.x*(1.f/4096.f), sv.x, sv.y), 0.f);
  }
  s4[wid*64 + rl] = acc;
  __syncthreads();
  if (tid < 64)
    out[(size_t)blockIdx.x*64 + tid] = (s4[tid] + s4[64+tid] + s4[128+tid] + s4[192+tid]) * (1.f/64.f);
}

extern "C" void kernel_launch(void* const* d_in, const int* in_sizes, int n_in,
                              void* d_out, int out_size, void* d_ws, size_t ws_size,
                              hipStream_t stream){
  const float* x   = (const float*)d_in[0];
  const float* ks2 = (const float*)d_in[1];
  const float* bs2 = (const float*)d_in[2];
  const float* k1  = (const float*)d_in[3];
  const float* b1c = (const float*)d_in[4];
  const float* k2  = (const float*)d_in[5];
  const float* b2c = (const float*)d_in[6];
  const float* k3  = (const float*)d_in[7];
  const float* b3c = (const float*)d_in[8];
  const float* g1 = (const float*)d_in[9],  *bb1 = (const float*)d_in[10];
  const float* g2 = (const float*)d_in[11], *bb2 = (const float*)d_in[12];
  const float* g3 = (const float*)d_in[13], *bb3 = (const float*)d_in[14];
  const float* g4 = (const float*)d_in[15], *bb4 = (const float*)d_in[16];
  float* out = (float*)d_out;

  char* w = (char*)d_ws;
  size_t off = 0;
  auto take = [&](size_t bytes)->char*{
    char* p = w + off;
    off += (bytes + 255) & ~(size_t)255;
    return p;
  };
  float*  Dz   = (float*) take(64ull*32*32*63*4);
  float*  Deq  = (float*) take(32ull*63*63*4);
  double* lf   = (double*)take(65*8);
  double* qw   = (double*)take(64*8);
  double* part = (double*)take(75ull*64*2*8);
  float2* ss   = (float2*)take(75*8);
  float2* KhS2 = (float2*)take(63ull*25*3*8);
  float2* Kh1  = (float2*)take(63ull*25*25*8);
  float2* Kh2  = (float2*)take(63ull*25*50*8);
  float2* Kh3  = (float2*)take(63ull*36*75*8);
  float2* XH2  = (float2*)take(2ull*3*64*63*8);
  float2* F2   = (float2*)take(2ull*3*32*63*8);
  ushortT* X1  = (ushortT*)take(2ull*25*262144*2);
  ushortT* X2  = (ushortT*)take(2ull*25*262144*2);
  ushortT* X3  = (ushortT*)take(2ull*25*262144*2);
  float2* A    = (float2*)take(150ull*32*2016*8);
  float2* B    = (float2*)take(150ull*32*2016*8);
  if (off > ws_size) return;

  dim3 tpb(TPB);
  auto cdiv = [](long long a, long long b){ return (int)((a + b - 1) / b); };

  k_tables<<<1, 64, 0, stream>>>(lf, qw);
  k_wigner<<<dim3(65,32), tpb, 0, stream>>>(lf, Dz, Deq);
  k_kh<<<cdiv(3ll*25*63,TPB),  tpb, 0, stream>>>(ks2, KhS2, 3, 25,  (float)(1.0/sqrt(196608.0)));
  k_kh<<<cdiv(25ll*25*63,TPB), tpb, 0, stream>>>(k1,  Kh1, 25, 25, (float)(1.0/sqrt(1600.0)));
  k_kh<<<cdiv(50ll*25*63,TPB), tpb, 0, stream>>>(k2,  Kh2, 50, 25, (float)(1.0/sqrt(3200.0)));
  k_kh<<<cdiv(75ll*36*63,TPB), tpb, 0, stream>>>(k3,  Kh3, 75, 36, (float)(1.0/sqrt(4800.0)));

  // ---- S2 conv ----
  k_s2_fft<<<cdiv(2ll*3*64*63,TPB), tpb, 0, stream>>>(x, XH2);
  k_s2_F<<<cdiv(2ll*3*32*63,TPB), tpb, 0, stream>>>(Dz, qw, XH2, F2);
  k_s2_zhat<<<cdiv(2ll*25*32*2016,TPB), tpb, 0, stream>>>(Deq, F2, KhS2, B);
  k_wig_synth<<<dim3(32,8,2*cdiv(50,16)), tpb, 0, stream>>>(Dz, B, A, 50);
  k_ifft2_sym<<<50*64, tpb, 0, stream>>>(A, X1, bs2, 25);

  // ---- generic SO3 conv ----
  auto so3 = [&](const ushortT* Xa, const ushortT* Xb, const ushortT* Xc, int Cin,
                 const float* g, const float* bb, const float2* Kh, int O,
                 const float* bias, ushortT* Xout, int isFinal){
    int BC = 2*Cin, BO = 2*O;
    k_bnstats<<<dim3(25,64), tpb, 0, stream>>>(Xa, 0, part);
    if (Cin > 25) k_bnstats<<<dim3(25,64), tpb, 0, stream>>>(Xb, 25, part);
    if (Cin > 50) k_bnstats<<<dim3(25,64), tpb, 0, stream>>>(Xc, 50, part);
    k_bnfinal<<<1, 128, 0, stream>>>(part, g, bb, ss, Cin);
    for (int z0 = 0; z0 < 64; z0 += 32){
      k_fft2_fwd<<<dim3(BC,32), tpb, 0, stream>>>(Xa, Xb, Xc, ss, A, Cin, z0);
      k_wig_F<<<dim3(32,8,cdiv(BC,16)), tpb, 0, stream>>>(Dz, qw, A, B, BC, z0, z0 > 0 ? 1 : 0);
    }
    k_deq_C<<<dim3(32,32,cdiv(BC,64)), tpb, 0, stream>>>(Deq, B, A, BC);
    k_kh_z<<<dim3(32,32), tpb, 0, stream>>>(A, Kh, B, Cin, O);
    k_wig_synth<<<dim3(32,8,2*cdiv(BO,16)), tpb, 0, stream>>>(Dz, B, A, BO);
    if (!isFinal){
      k_ifft2_sym<<<BO*64, tpb, 0, stream>>>(A, Xout, bias, O);
    } else {
      k_stats3<<<dim3(BO,16), tpb, 0, stream>>>(A, part);
      k_fstat<<<1, 64, 0, stream>>>(part, bias, g4, bb4, ss, O);
      k_final<<<BO*64, tpb, 0, stream>>>(A, ss, out, O);
    }
  };

  so3(X1, X1, X1, 25, g1, bb1, Kh1, 25, b1c, X2, 0);
  so3(X1, X2, X2, 50, g2, bb2, Kh2, 25, b2c, X3, 0);
  so3(X1, X2, X3, 75, g3, bb3, Kh3, 36, b3c, nullptr, 1);
}

// Round 5
// 2229.189 us; speedup vs baseline: 2.2980x; 1.1023x over previous
//
#include <hip/hip_runtime.h>
#include <math.h>

#define PI_D 3.14159265358979323846
#define TPB 256
typedef unsigned short ushortT;
typedef unsigned int uintT;

__device__ __forceinline__ float2 cxmul(float2 a, float2 b){
  return make_float2(a.x*b.x - a.y*b.y, a.x*b.y + a.y*b.x);
}
__device__ __forceinline__ float bf2f(ushortT u){
  uintT x = ((uintT)u) << 16;
  return __uint_as_float(x);
}
__device__ __forceinline__ ushortT f2bf(float f){
  uintT x = __float_as_uint(f);
  x = x + 0x7FFFu + ((x >> 16) & 1u);
  return (ushortT)(x >> 16);
}

// ---------------- tables ----------------
__global__ void k_tables(double* lf, double* qw){
  if (threadIdx.x == 0){
    lf[0] = 0.0;
    for (int i = 1; i <= 64; ++i) lf[i] = lf[i-1] + log((double)i);
  }
  int j = threadIdx.x;
  if (j < 64){
    double s1 = sin(PI_D*(2*j+1)/128.0);
    double inner = 0.0;
    for (int k = 0; k < 32; ++k)
      inner += (1.0/(double)(2*k+1)) * sin((double)(2*j+1)*(double)(2*k+1)*PI_D/128.0);
    qw[j] = (2.0/32.0) * s1 * inner;
  }
}

__device__ double wigd(const double* lfs, int l, int mp, int m, double lc, double ls){
  if (mp < -l || mp > l || m < -l || m > l) return 0.0;
  int k0 = (m - mp > 0) ? (m - mp) : 0;
  int k1 = (l + m < l - mp) ? (l + m) : (l - mp);
  double base = 0.5*(lfs[l+mp] + lfs[l-mp] + lfs[l+m] + lfs[l-m]);
  double val = 0.0;
  for (int k = k0; k <= k1; ++k){
    double t = base - lfs[l+m-k] - lfs[k] - lfs[mp-m+k] - lfs[l-mp-k]
             + (double)(2*l + m - mp - 2*k)*lc + (double)(mp - m + 2*k)*ls;
    double e = exp(t);
    val += ((mp - m + k) & 1) ? -e : e;
  }
  return val;
}

// Dz[z][l][mi'][n], Deq[l][r][c]
__global__ __launch_bounds__(TPB) void k_wigner(const double* __restrict__ lf,
                                                float* __restrict__ Dz, float* __restrict__ Deq){
  __shared__ double lfs[65];
  if (threadIdx.x < 65) lfs[threadIdx.x] = lf[threadIdx.x];
  __syncthreads();
  int zs = blockIdx.x, l = blockIdx.y;
  double beta = (zs < 64) ? ((double)zs + 0.5)*PI_D/64.0 : PI_D*0.5;
  double ch = cos(beta*0.5), sh = sin(beta*0.5);
  double lc = log(ch), ls = log(sh);
  if (zs < 64){
    for (int idx = threadIdx.x; idx < 2016; idx += TPB){
      int mi = idx/63, c = idx%63;
      Dz[((size_t)(zs*32 + l)*32 + mi)*63 + c] = (float)wigd(lfs, l, mi, c-31, lc, ls);
    }
  } else {
    for (int idx = threadIdx.x; idx < 3969; idx += TPB){
      int r = idx/63, c = idx%63;
      Deq[((size_t)l*63 + r)*63 + c] = (float)wigd(lfs, l, r-31, c-31, lc, ls);
    }
  }
}

// Kh[o][i][n] = scale * sum_p K[i,o,p] * exp(-i*2pi*p*(n-31)/64)
__global__ void k_kh(const float* __restrict__ K, float2* __restrict__ Kh, int I, int O, float scale){
  int idx = blockIdx.x*blockDim.x + threadIdx.x;
  if (idx >= I*O*63) return;
  int n = idx % 63, i = (idx/63) % I, o = idx/(63*I);
  float sr = 0.f, si = 0.f;
  for (int p = 0; p < 64; ++p){
    int t = (p * (n - 31)) & 63;
    float s, c;
    sincosf(-(float)PI_D/32.f * (float)t, &s, &c);
    float kv = K[(i*O + o)*64 + p];
    sr += kv * c; si += kv * s;
  }
  Kh[((size_t)o*I + i)*63 + n] = make_float2(sr*scale, si*scale);
}

// ---------------- S2 front ----------------
__global__ void k_s2_fft(const float* __restrict__ x, float2* __restrict__ XH2){
  int idx = blockIdx.x*blockDim.x + threadIdx.x;
  if (idx >= 2*3*64*63) return;
  int mi = idx % 63; int z = (idx/63) & 63; int bc = idx / (63*64);
  int f = (mi + 33) & 63;
  const float* row = x + ((size_t)bc*64 + z)*64;
  float sr = 0.f, si = 0.f;
  for (int a = 0; a < 64; ++a){
    int t = (f*a) & 63;
    float s, c;
    sincosf(-(float)PI_D/32.f * (float)t, &s, &c);
    sr += row[a]*c; si += row[a]*s;
  }
  XH2[idx] = make_float2(sr, si);
}

__global__ void k_s2_F(const float* __restrict__ Dz, const double* __restrict__ qw,
                       const float2* __restrict__ XH2, float2* __restrict__ F2){
  int idx = blockIdx.x*blockDim.x + threadIdx.x;
  if (idx >= 2*3*32*63) return;
  int r = idx % 63; int l = (idx/63) & 31; int bc = idx / (63*32);
  float2 acc = make_float2(0,0);
  for (int z = 0; z < 64; ++z){
    float d;
    if (r >= 31) d = Dz[((size_t)(z*32 + l)*32 + (r-31))*63 + 31];
    else {
      d = Dz[((size_t)(z*32 + l)*32 + (31-r))*63 + 31];
      if ((31-r) & 1) d = -d;
    }
    float wv = (float)qw[z] * d;
    float2 v = XH2[((size_t)bc*64 + z)*63 + r];
    acc.x += wv*v.x; acc.y += wv*v.y;
  }
  F2[idx] = acc;
}

__global__ void k_s2_zhat(const float* __restrict__ Deq, const float2* __restrict__ F2,
                          const float2* __restrict__ Kh, float2* __restrict__ Z){
  int idx = blockIdx.x*blockDim.x + threadIdx.x;
  if (idx >= 2*25*32*2016) return;
  int n = idx % 63; int mi = (idx/63) & 31; int l = (idx/2016) & 31;
  int o = (idx/(2016*32)) % 25; int b = idx/(2016*32*25);
  float deq0 = Deq[((size_t)l*63 + n)*63 + 31];
  float2 acc = make_float2(0,0);
  for (int i = 0; i < 3; ++i){
    float2 f = F2[((size_t)(b*3 + i)*32 + l)*63 + (mi+31)];
    float2 kh = Kh[((size_t)(o*3 + i))*63 + n];
    float2 p = cxmul(f, kh);
    acc.x += p.x; acc.y += p.y;
  }
  Z[((size_t)((b*25+o)*32) + l)*2016 + mi*63 + n] = make_float2(acc.x*deq0, acc.y*deq0);
}

// ---------------- BN stats over bf16 X buffers ----------------
__global__ __launch_bounds__(TPB) void k_bnstats(const ushortT* __restrict__ src, int slotBase,
                                                 double* __restrict__ part){
  int c = blockIdx.x, blk = blockIdx.y;
  const uint2* s4 = (const uint2*)src;
  double s = 0.0, q = 0.0;
  for (int k = 0; k < 8; ++k){
    int g4 = blk*2048 + k*256 + threadIdx.x;
    int b = g4 >> 16, pos4 = g4 & 65535;
    uint2 u = s4[((size_t)(b*25 + c))*65536 + pos4];
    float v0 = bf2f((ushortT)(u.x & 0xffff)), v1 = bf2f((ushortT)(u.x >> 16));
    float v2 = bf2f((ushortT)(u.y & 0xffff)), v3 = bf2f((ushortT)(u.y >> 16));
    s += (double)v0 + v1 + v2 + v3;
    q += (double)v0*v0 + (double)v1*v1 + (double)v2*v2 + (double)v3*v3;
  }
  __shared__ double sh[TPB], sh2[TPB];
  sh[threadIdx.x] = s; sh2[threadIdx.x] = q;
  __syncthreads();
  for (int o = 128; o > 0; o >>= 1){
    if (threadIdx.x < o){ sh[threadIdx.x] += sh[threadIdx.x+o]; sh2[threadIdx.x] += sh2[threadIdx.x+o]; }
    __syncthreads();
  }
  if (threadIdx.x == 0){
    part[((size_t)(slotBase + c)*64 + blk)*2 + 0] = sh[0];
    part[((size_t)(slotBase + c)*64 + blk)*2 + 1] = sh2[0];
  }
}

__global__ void k_bnfinal(const double* __restrict__ part, const float* __restrict__ g,
                          const float* __restrict__ b, float2* __restrict__ ss, int C){
  int c = blockIdx.x*blockDim.x + threadIdx.x;
  if (c >= C) return;
  double s = 0.0, q = 0.0;
  for (int k = 0; k < 64; ++k){
    s += part[((size_t)c*64 + k)*2 + 0];
    q += part[((size_t)c*64 + k)*2 + 1];
  }
  double N = 524288.0;
  double mu = s / N;
  double var = q / N - mu*mu;
  double sc = (double)g[c] / sqrt(var + 1e-5);
  ss[c] = make_float2((float)sc, (float)((double)b[c] - mu*sc));
}

// ---------------- 64-pt FFT across lanes (radix-2 DIF, shfl) ----------------
__device__ __forceinline__ float2 fft64_lane(float2 x, const float2* __restrict__ Wt, int lane){
  #pragma unroll
  for (int st = 0; st < 6; ++st){
    int h = 32 >> st;
    float2 p;
    p.x = __shfl_xor(x.x, h, 64);
    p.y = __shfl_xor(x.y, h, 64);
    if (lane & h){
      float2 s = make_float2(p.x - x.x, p.y - x.y);
      x = cxmul(s, Wt[(lane & (h-1)) << st]);
    } else {
      x = make_float2(x.x + p.x, x.y + p.y);
    }
  }
  return x;
}
__device__ __forceinline__ void init_W(float2* W, float sign){
  if (threadIdx.x < 64){
    float s, c;
    sincosf(sign*(float)(2.0*PI_D/64.0)*(float)threadIdx.x, &s, &c);
    W[threadIdx.x] = make_float2(c, s);
  }
}

// ---------------- fused BN+ReLU + fft2 + reduced centered extraction ----------------
__global__ __launch_bounds__(TPB) void k_fft2_fwd(const ushortT* __restrict__ X1, const ushortT* __restrict__ X2,
                                                  const ushortT* __restrict__ X3, const float2* __restrict__ ss,
                                                  float2* __restrict__ XH, int Cin, int z0){
  __shared__ float2 W[64];
  __shared__ __attribute__((aligned(16))) float2 buf[64*65];
  int bc = blockIdx.x, zz = blockIdx.y, z = z0 + zz;
  int b = bc / Cin, ci = bc % Cin;
  const ushortT* src; int cl;
  if (ci < 25){ src = X1; cl = ci; }
  else if (ci < 50){ src = X2; cl = ci - 25; }
  else { src = X3; cl = ci - 50; }
  src += ((size_t)(b*25 + cl)*64 + z)*4096;
  float2 sc = ss[ci];
  init_W(W, -1.f);
  int tid = threadIdx.x, lane = tid & 63, wid = tid >> 6;
  int rl = (int)(__brev((uintT)lane) >> 26);
  const uintT* s32 = (const uintT*)src;
  for (int i = tid; i < 2048; i += TPB){
    uintT u = s32[i];
    float v0 = fmaxf(bf2f((ushortT)(u & 0xffff))*sc.x + sc.y, 0.f);
    float v1 = fmaxf(bf2f((ushortT)(u >> 16))*sc.x + sc.y, 0.f);
    int row = i >> 5, col = (i << 1) & 63;
    buf[row*65 + col]     = make_float2(v0, 0.f);
    buf[row*65 + col + 1] = make_float2(v1, 0.f);
  }
  __syncthreads();
  #pragma unroll 4
  for (int i = 0; i < 16; ++i){
    int r = wid*16 + i;
    float2 x = buf[r*65 + lane];
    x = fft64_lane(x, W, lane);
    buf[r*65 + rl] = x;
  }
  __syncthreads();
  #pragma unroll 4
  for (int i = 0; i < 16; ++i){
    int c = wid*16 + i;
    float2 x = buf[lane*65 + c];
    x = fft64_lane(x, W, lane);
    buf[rl*65 + c] = x;
  }
  __syncthreads();
  float2* dst = XH + ((size_t)bc*32 + zz)*2016;
  for (int idx = tid; idx < 2016; idx += TPB){
    int mi = idx / 63, n = idx % 63;
    dst[idx] = buf[mi*65 + ((n+33)&63)];
  }
}

// ---------------- F[bc,l,mi,n] (+)= sum_z qw*Dz*XH — register-tiled ----------------
// grid (32 mi, 8 nt, ceil(BC/16)); block 256
__global__ __launch_bounds__(TPB) void k_wig_F(const float* __restrict__ Dz, const double* __restrict__ qw,
                                               const float2* __restrict__ XH, float2* __restrict__ F,
                                               int BC, int z0, int accum){
  __shared__ __attribute__((aligned(16))) float sm[9088];
  float* Dt = sm;                          // [z16][nn8][l 36pad]
  float2* Xt = (float2*)(sm + 4608);       // [bc16][130]
  int mi = blockIdx.x, nt = blockIdx.y, bcBase = blockIdx.z*16;
  int tid = threadIdx.x;
  int bg = tid & 3, lg = (tid>>2)&7, ng = tid>>5;
  float2 acc[4][4];
  #pragma unroll
  for (int a = 0; a < 4; ++a)
    #pragma unroll
    for (int j = 0; j < 4; ++j) acc[a][j] = make_float2(0,0);
  for (int zq = 0; zq < 32; zq += 16){
    __syncthreads();
    for (int idx = tid; idx < 4096; idx += TPB){
      int z = idx >> 8, l = (idx>>3)&31, nn = idx&7;
      int n = nt*8 + nn;
      float v = 0.f;
      if (n < 63) v = Dz[(((size_t)(z0+zq+z)*32 + l)*32 + mi)*63 + n] * (float)qw[z0+zq+z];
      Dt[(z*8+nn)*36 + l] = v;
    }
    for (int idx = tid; idx < 2048; idx += TPB){
      int bc = idx >> 7, z = (idx>>3)&15, nn = idx&7;
      int gbc = bcBase + bc, n = nt*8 + nn;
      float2 v = make_float2(0,0);
      if (gbc < BC && n < 63) v = XH[((size_t)gbc*32 + zq + z)*2016 + mi*63 + n];
      Xt[bc*130 + z*8 + nn] = v;
    }
    __syncthreads();
    #pragma unroll 4
    for (int z = 0; z < 16; ++z){
      const float4 d = *(const float4*)&Dt[(z*8+ng)*36 + lg*4];
      float dd[4] = {d.x, d.y, d.z, d.w};
      float2 xv[4];
      #pragma unroll
      for (int j = 0; j < 4; ++j) xv[j] = Xt[(bg + 4*j)*130 + z*8 + ng];
      #pragma unroll
      for (int j = 0; j < 4; ++j)
        #pragma unroll
        for (int dl = 0; dl < 4; ++dl){
          acc[j][dl].x += dd[dl]*xv[j].x;
          acc[j][dl].y += dd[dl]*xv[j].y;
        }
    }
  }
  __syncthreads();
  float2* St = (float2*)sm;                // [bc16][l32][nn8]
  #pragma unroll
  for (int j = 0; j < 4; ++j)
    #pragma unroll
    for (int dl = 0; dl < 4; ++dl)
      St[(((bg + 4*j)*32) + lg*4 + dl)*8 + ng] = acc[j][dl];
  __syncthreads();
  for (int idx = tid; idx < 4096; idx += TPB){
    int bc = idx >> 8, l = (idx>>3)&31, nn = idx&7;
    int gbc = bcBase + bc, n = nt*8 + nn;
    if (gbc < BC && n < 63){
      size_t a = ((size_t)(gbc*32 + l))*2016 + mi*63 + n;
      float2 v = St[idx];
      if (accum){ float2 o = F[a]; v.x += o.x; v.y += o.y; }
      F[a] = v;
    }
  }
}

// ---------------- C[bi,l,mi,n] = sum_k F[bi,l,mi,k]*Deq[l,n,k] — register-tiled ----------------
// grid (32 l, 32 mi, ceil(BC/64)); block 256
__global__ __launch_bounds__(TPB) void k_deq_C(const float* __restrict__ Deq, const float2* __restrict__ F,
                                               float2* __restrict__ C, int BC){
  __shared__ __attribute__((aligned(16))) float sm[12604];
  float2* Fb = (float2*)sm;                // [bi64][65pad]
  float* DeqT = sm + 8320;                 // [k63][68pad n]
  int l = blockIdx.x, mi = blockIdx.y, biBase = blockIdx.z*64;
  int tid = threadIdx.x;
  int ngr = tid & 15, big = tid >> 4;
  for (int idx = tid; idx < 3969; idx += TPB){
    int n = idx/63, k = idx - n*63;
    DeqT[k*68 + n] = Deq[((size_t)l*63 + n)*63 + k];
  }
  for (int idx = tid; idx < 4032; idx += TPB){
    int bi = idx/63, k = idx - bi*63;
    int gbi = biBase + bi;
    Fb[bi*65 + k] = (gbi < BC) ? F[((size_t)(gbi*32 + l))*2016 + mi*63 + k] : make_float2(0,0);
  }
  __syncthreads();
  float2 acc[4][4];
  #pragma unroll
  for (int a = 0; a < 4; ++a)
    #pragma unroll
    for (int j = 0; j < 4; ++j) acc[a][j] = make_float2(0,0);
  #pragma unroll 3
  for (int k = 0; k < 63; ++k){
    const float4 d = *(const float4*)&DeqT[k*68 + ngr*4];
    float dd[4] = {d.x, d.y, d.z, d.w};
    float2 fv[4];
    #pragma unroll
    for (int j = 0; j < 4; ++j) fv[j] = Fb[(big + 16*j)*65 + k];
    #pragma unroll
    for (int j = 0; j < 4; ++j)
      #pragma unroll
      for (int dn = 0; dn < 4; ++dn){
        acc[j][dn].x += dd[dn]*fv[j].x;
        acc[j][dn].y += dd[dn]*fv[j].y;
      }
  }
  __syncthreads();
  float2* St = (float2*)sm;                // [bi64][n63]
  #pragma unroll
  for (int j = 0; j < 4; ++j)
    #pragma unroll
    for (int dn = 0; dn < 4; ++dn){
      int n = ngr*4 + dn;
      if (n < 63) St[(big + 16*j)*63 + n] = acc[j][dn];
    }
  __syncthreads();
  for (int idx = tid; idx < 4032; idx += TPB){
    int bi = idx/63, n = idx - bi*63;
    int gbi = biBase + bi;
    if (gbi < BC) C[((size_t)(gbi*32 + l))*2016 + mi*63 + n] = St[idx];
  }
}

// ---------------- Z[b,o,l,mi,n] = sum_i Kh[o,i,n]*C[b,i,l,mi,n] — LDS-staged Kh ----------------
// grid (32 l, 8 mic, 3 nc); block 256 (252 compute-active)
__global__ __launch_bounds__(TPB) void k_kh_z(const float2* __restrict__ C, const float2* __restrict__ Kh,
                                              float2* __restrict__ Z, int I, int O){
  __shared__ float2 Kt[3024];   // [o<=36][i4][nn21]
  __shared__ float2 Ct[672];    // [i4][b2][mi4][nn21]
  int l = blockIdx.x, mic = blockIdx.y, n0 = blockIdx.z*21;
  int tid = threadIdx.x;
  int og = tid/21, nn = tid - og*21;
  float2 acc[3][8];
  #pragma unroll
  for (int r = 0; r < 3; ++r)
    #pragma unroll
    for (int c = 0; c < 8; ++c) acc[r][c] = make_float2(0,0);
  int kElems = O*84;
  for (int i0 = 0; i0 < I; i0 += 4){
    __syncthreads();
    for (int idx = tid; idx < kElems; idx += TPB){
      int o = idx/84, rr = idx - o*84;
      int i = i0 + rr/21, n2 = rr%21;
      Kt[idx] = (i < I) ? Kh[((size_t)o*I + i)*63 + n0 + n2] : make_float2(0,0);
    }
    for (int idx = tid; idx < 672; idx += TPB){
      int i = idx/168, rem = idx - i*168;
      int b = rem/84, rem2 = rem - b*84;
      int mi = rem2/21, n2 = rem2 - mi*21;
      int gi = i0 + i;
      Ct[idx] = (gi < I) ? C[((size_t)((b*I+gi)*32) + l)*2016 + (mic*4+mi)*63 + n0 + n2]
                         : make_float2(0,0);
    }
    __syncthreads();
    if (og < 12){
      #pragma unroll
      for (int i = 0; i < 4; ++i){
        float2 kh[3];
        #pragma unroll
        for (int r = 0; r < 3; ++r) kh[r] = Kt[((og + 12*r)*4 + i)*21 + nn];
        #pragma unroll
        for (int b = 0; b < 2; ++b)
          #pragma unroll
          for (int mi = 0; mi < 4; ++mi){
            float2 cv = Ct[((i*2 + b)*4 + mi)*21 + nn];
            #pragma unroll
            for (int r = 0; r < 3; ++r){
              acc[r][b*4+mi].x += kh[r].x*cv.x - kh[r].y*cv.y;
              acc[r][b*4+mi].y += kh[r].x*cv.y + kh[r].y*cv.x;
            }
          }
      }
    }
  }
  if (og < 12){
    #pragma unroll
    for (int r = 0; r < 3; ++r){
      int o = og + 12*r;
      if (o < O){
        #pragma unroll
        for (int b = 0; b < 2; ++b)
          #pragma unroll
          for (int mi = 0; mi < 4; ++mi)
            Z[((size_t)((b*O+o)*32) + l)*2016 + (mic*4+mi)*63 + n0 + nn] = acc[r][b*4+mi];
      }
    }
  }
}

// ---------------- Xt[bo,z,mi,n] = sum_l wl*Dz*Z — register-tiled ----------------
// grid (32 mi, 8 nt, 2*ceil(BO/16)); block 256
__global__ __launch_bounds__(TPB) void k_wig_synth(const float* __restrict__ Dz, const float2* __restrict__ Z,
                                                   float2* __restrict__ Xt_g, int BO){
  __shared__ __attribute__((aligned(16))) float sm[9088];
  float* Dt = sm;                          // [l16][nn8][z 36pad]
  float2* Zt = (float2*)(sm + 4608);       // [bo16][130]
  int mi = blockIdx.x, nt = blockIdx.y;
  int z0 = (blockIdx.z & 1)*32;
  int boBase = (blockIdx.z >> 1)*16;
  int tid = threadIdx.x;
  int bg = tid & 3, zg = (tid>>2)&7, ng = tid>>5;
  float2 acc[4][4];
  #pragma unroll
  for (int a = 0; a < 4; ++a)
    #pragma unroll
    for (int j = 0; j < 4; ++j) acc[a][j] = make_float2(0,0);
  for (int lq = 0; lq < 32; lq += 16){
    __syncthreads();
    for (int idx = tid; idx < 4096; idx += TPB){
      int ll = idx >> 8, z = (idx>>3)&31, nn = idx&7;
      int n = nt*8 + nn, lG = lq + ll;
      float v = 0.f;
      if (n < 63) v = Dz[(((size_t)(z0+z)*32 + lG)*32 + mi)*63 + n] * (0.5f*(float)(2*lG+1));
      Dt[(ll*8+nn)*36 + z] = v;
    }
    for (int idx = tid; idx < 2048; idx += TPB){
      int bo = idx >> 7, ll = (idx>>3)&15, nn = idx&7;
      int gbo = boBase + bo, n = nt*8 + nn;
      float2 v = make_float2(0,0);
      if (gbo < BO && n < 63) v = Z[((size_t)(gbo*32 + lq + ll))*2016 + mi*63 + n];
      Zt[bo*130 + ll*8 + nn] = v;
    }
    __syncthreads();
    #pragma unroll 4
    for (int ll = 0; ll < 16; ++ll){
      const float4 d = *(const float4*)&Dt[(ll*8+ng)*36 + zg*4];
      float dd[4] = {d.x, d.y, d.z, d.w};
      float2 zv[4];
      #pragma unroll
      for (int j = 0; j < 4; ++j) zv[j] = Zt[(bg + 4*j)*130 + ll*8 + ng];
      #pragma unroll
      for (int j = 0; j < 4; ++j)
        #pragma unroll
        for (int dz = 0; dz < 4; ++dz){
          acc[j][dz].x += dd[dz]*zv[j].x;
          acc[j][dz].y += dd[dz]*zv[j].y;
        }
    }
  }
  __syncthreads();
  float2* St = (float2*)sm;                // [bo16][z32][nn8]
  #pragma unroll
  for (int j = 0; j < 4; ++j)
    #pragma unroll
    for (int dz = 0; dz < 4; ++dz)
      St[(((bg + 4*j)*32) + zg*4 + dz)*8 + ng] = acc[j][dz];
  __syncthreads();
  for (int idx = tid; idx < 4096; idx += TPB){
    int bo = idx >> 8, z = (idx>>3)&31, nn = idx&7;
    int gbo = boBase + bo, n = nt*8 + nn;
    if (gbo < BO && n < 63)
      Xt_g[((size_t)gbo*64 + z0 + z)*2016 + mi*63 + n] = St[idx];
  }
}

// ---------------- coalesced Hermitian build ----------------
__device__ __forceinline__ void build_plane_c(const float2* __restrict__ src, float2* buf){
  int tid = threadIdx.x;
  if (tid < 128){
    int k = tid & 63;
    if (tid < 64) buf[32*65 + k] = make_float2(0,0);
    else          buf[k*65 + 32] = make_float2(0,0);
  }
  for (int idx = tid; idx < 2016; idx += TPB){
    float2 v = src[idx];
    int mi = idx / 63, ni = idx - mi*63;
    buf[mi*65 + ((ni+33)&63)] = v;
    if (mi > 0) buf[(64-mi)*65 + ((31-ni)&63)] = make_float2(v.x, -v.y);
  }
}

// ---------------- ifft2 + real + bias -> bf16 X ----------------
__global__ __launch_bounds__(TPB) void k_ifft2_sym(const float2* __restrict__ Xt, ushortT* __restrict__ Xo,
                                                   const float* __restrict__ bias, int O){
  __shared__ float2 W[64];
  __shared__ __attribute__((aligned(16))) float2 buf[64*65];
  int bo = blockIdx.x >> 6;
  int o = bo % O;
  init_W(W, 1.f);
  int tid = threadIdx.x, lane = tid & 63, wid = tid >> 6;
  int rl = (int)(__brev((uintT)lane) >> 26);
  const float2* src = Xt + (size_t)blockIdx.x*2016;
  build_plane_c(src, buf);
  __syncthreads();
  #pragma unroll 4
  for (int i = 0; i < 16; ++i){
    int r = wid*16 + i;
    float2 x = buf[r*65 + lane];
    x = fft64_lane(x, W, lane);
    buf[r*65 + rl] = x;
  }
  __syncthreads();
  #pragma unroll 4
  for (int i = 0; i < 16; ++i){
    int c = wid*16 + i;
    float2 x = buf[lane*65 + c];
    x = fft64_lane(x, W, lane);
    buf[rl*65 + c] = x;
  }
  __syncthreads();
  float bb = bias[o];
  ushortT* dst = Xo + (size_t)blockIdx.x*4096;
  for (int idx = tid; idx < 4096; idx += TPB){
    dst[idx] = f2bf(buf[(idx>>6)*65 + (idx&63)].x * (1.f/4096.f) + bb);
  }
}

// ---------------- conv3 final stats from spectrum (Parseval) ----------------
__global__ __launch_bounds__(TPB) void k_stats3(const float2* __restrict__ Xt, double* __restrict__ part){
  int bo = blockIdx.x, zb = blockIdx.y;
  double s = 0.0, p = 0.0;
  for (int zz = 0; zz < 4; ++zz){
    const float2* pl = Xt + ((size_t)bo*64 + zb*4 + zz)*2016;
    for (int idx = threadIdx.x; idx < 2016; idx += TPB){
      float2 v = pl[idx];
      double q = (double)v.x*v.x + (double)v.y*v.y;
      p += (idx < 63) ? q : 2.0*q;
      if (idx == 31) s += v.x;
    }
  }
  __shared__ double sh[TPB], sh2[TPB];
  sh[threadIdx.x] = s; sh2[threadIdx.x] = p;
  __syncthreads();
  for (int o = 128; o > 0; o >>= 1){
    if (threadIdx.x < o){ sh[threadIdx.x] += sh[threadIdx.x+o]; sh2[threadIdx.x] += sh2[threadIdx.x+o]; }
    __syncthreads();
  }
  if (threadIdx.x == 0){
    part[((size_t)bo*16 + zb)*2 + 0] = sh[0];
    part[((size_t)bo*16 + zb)*2 + 1] = sh2[0];
  }
}

__global__ void k_fstat(const double* __restrict__ part, const float* __restrict__ bias,
                        const float* __restrict__ g, const float* __restrict__ bsh,
                        float2* __restrict__ ss, int O){
  int o = threadIdx.x;
  if (o >= O) return;
  double S = 0.0, P = 0.0;
  for (int b = 0; b < 2; ++b)
    for (int zb = 0; zb < 16; ++zb){
      size_t base = ((size_t)(b*O + o)*16 + zb)*2;
      S += part[base]; P += part[base+1];
    }
  P *= (1.0/4096.0);
  double N = 524288.0;
  double bi = bias[o];
  double mean = S/N + bi;
  double var = P/N + 2.0*bi*S/N + bi*bi - mean*mean;
  double sc = (double)g[o] / sqrt(var + 1e-5);
  ss[o] = make_float2((float)sc, (float)((bi - mean)*sc + (double)bsh[o]));
}

// ---------------- fused ifft2 + BN + ReLU + mean over gamma ----------------
__global__ __launch_bounds__(TPB) void k_final(const float2* __restrict__ Xt, const float2* __restrict__ ss,
                                               float* __restrict__ out, int O){
  __shared__ float2 W[64];
  __shared__ __attribute__((aligned(16))) float2 buf[64*65];
  __shared__ float s4[4*64];
  int bo = blockIdx.x >> 6;
  int o = bo % O;
  init_W(W, 1.f);
  int tid = threadIdx.x, lane = tid & 63, wid = tid >> 6;
  int rl = (int)(__brev((uintT)lane) >> 26);
  const float2* src = Xt + (size_t)blockIdx.x*2016;
  build_plane_c(src, buf);
  __syncthreads();
  #pragma unroll 4
  for (int i = 0; i < 16; ++i){
    int r = wid*16 + i;
    float2 x = buf[r*65 + lane];
    x = fft64_lane(x, W, lane);
    buf[r*65 + rl] = x;
  }
  __syncthreads();
  float2 sv = ss[o];
  float acc = 0.f;
  #pragma unroll 4
  for (int i = 0; i < 16; ++i){
    int c = wid*16 + i;
    float2 x = buf[lane*65 + c];
    x = fft64_lane(x, W, lane);
    acc += fmaxf(fmaf(x.x*(1.f/4096.f), sv.x, sv.y), 0.f);
  }
  s4[wid*64 + rl] = acc;
  __syncthreads();
  if (tid < 64)
    out[(size_t)blockIdx.x*64 + tid] = (s4[tid] + s4[64+tid] + s4[128+tid] + s4[192+tid]) * (1.f/64.f);
}

extern "C" void kernel_launch(void* const* d_in, const int* in_sizes, int n_in,
                              void* d_out, int out_size, void* d_ws, size_t ws_size,
                              hipStream_t stream){
  const float* x   = (const float*)d_in[0];
  const float* ks2 = (const float*)d_in[1];
  const float* bs2 = (const float*)d_in[2];
  const float* k1  = (const float*)d_in[3];
  const float* b1c = (const float*)d_in[4];
  const float* k2  = (const float*)d_in[5];
  const float* b2c = (const float*)d_in[6];
  const float* k3  = (const float*)d_in[7];
  const float* b3c = (const float*)d_in[8];
  const float* g1 = (const float*)d_in[9],  *bb1 = (const float*)d_in[10];
  const float* g2 = (const float*)d_in[11], *bb2 = (const float*)d_in[12];
  const float* g3 = (const float*)d_in[13], *bb3 = (const float*)d_in[14];
  const float* g4 = (const float*)d_in[15], *bb4 = (const float*)d_in[16];
  float* out = (float*)d_out;

  char* w = (char*)d_ws;
  size_t off = 0;
  auto take = [&](size_t bytes)->char*{
    char* p = w + off;
    off += (bytes + 255) & ~(size_t)255;
    return p;
  };
  float*  Dz   = (float*) take(64ull*32*32*63*4);
  float*  Deq  = (float*) take(32ull*63*63*4);
  double* lf   = (double*)take(65*8);
  double* qw   = (double*)take(64*8);
  double* part = (double*)take(75ull*64*2*8);
  float2* ss   = (float2*)take(75*8);
  float2* KhS2 = (float2*)take(63ull*25*3*8);
  float2* Kh1  = (float2*)take(63ull*25*25*8);
  float2* Kh2  = (float2*)take(63ull*25*50*8);
  float2* Kh3  = (float2*)take(63ull*36*75*8);
  float2* XH2  = (float2*)take(2ull*3*64*63*8);
  float2* F2   = (float2*)take(2ull*3*32*63*8);
  ushortT* X1  = (ushortT*)take(2ull*25*262144*2);
  ushortT* X2  = (ushortT*)take(2ull*25*262144*2);
  ushortT* X3  = (ushortT*)take(2ull*25*262144*2);
  float2* A    = (float2*)take(150ull*32*2016*8);
  float2* B    = (float2*)take(150ull*32*2016*8);
  if (off > ws_size) return;

  dim3 tpb(TPB);
  auto cdiv = [](long long a, long long b){ return (int)((a + b - 1) / b); };

  k_tables<<<1, 64, 0, stream>>>(lf, qw);
  k_wigner<<<dim3(65,32), tpb, 0, stream>>>(lf, Dz, Deq);
  k_kh<<<cdiv(3ll*25*63,TPB),  tpb, 0, stream>>>(ks2, KhS2, 3, 25,  (float)(1.0/sqrt(196608.0)));
  k_kh<<<cdiv(25ll*25*63,TPB), tpb, 0, stream>>>(k1,  Kh1, 25, 25, (float)(1.0/sqrt(1600.0)));
  k_kh<<<cdiv(50ll*25*63,TPB), tpb, 0, stream>>>(k2,  Kh2, 50, 25, (float)(1.0/sqrt(3200.0)));
  k_kh<<<cdiv(75ll*36*63,TPB), tpb, 0, stream>>>(k3,  Kh3, 75, 36, (float)(1.0/sqrt(4800.0)));

  // ---- S2 conv ----
  k_s2_fft<<<cdiv(2ll*3*64*63,TPB), tpb, 0, stream>>>(x, XH2);
  k_s2_F<<<cdiv(2ll*3*32*63,TPB), tpb, 0, stream>>>(Dz, qw, XH2, F2);
  k_s2_zhat<<<cdiv(2ll*25*32*2016,TPB), tpb, 0, stream>>>(Deq, F2, KhS2, B);
  k_wig_synth<<<dim3(32,8,2*cdiv(50,16)), tpb, 0, stream>>>(Dz, B, A, 50);
  k_ifft2_sym<<<50*64, tpb, 0, stream>>>(A, X1, bs2, 25);
  k_bnstats<<<dim3(25,64), tpb, 0, stream>>>(X1, 0, part);

  // ---- generic SO3 conv (stats slots already filled) ----
  auto so3 = [&](const ushortT* Xa, const ushortT* Xb, const ushortT* Xc, int Cin,
                 const float* g, const float* bb, const float2* Kh, int O,
                 const float* bias, ushortT* Xout, int isFinal){
    int BC = 2*Cin, BO = 2*O;
    k_bnfinal<<<1, 128, 0, stream>>>(part, g, bb, ss, Cin);
    for (int z0 = 0; z0 < 64; z0 += 32){
      k_fft2_fwd<<<dim3(BC,32), tpb, 0, stream>>>(Xa, Xb, Xc, ss, A, Cin, z0);
      k_wig_F<<<dim3(32,8,cdiv(BC,16)), tpb, 0, stream>>>(Dz, qw, A, B, BC, z0, z0 > 0 ? 1 : 0);
    }
    k_deq_C<<<dim3(32,32,cdiv(BC,64)), tpb, 0, stream>>>(Deq, B, A, BC);
    k_kh_z<<<dim3(32,8,3), tpb, 0, stream>>>(A, Kh, B, Cin, O);
    k_wig_synth<<<dim3(32,8,2*cdiv(BO,16)), tpb, 0, stream>>>(Dz, B, A, BO);
    if (!isFinal){
      k_ifft2_sym<<<BO*64, tpb, 0, stream>>>(A, Xout, bias, O);
    } else {
      k_stats3<<<dim3(BO,16), tpb, 0, stream>>>(A, part);
      k_fstat<<<1, 64, 0, stream>>>(part, bias, g4, bb4, ss, O);
      k_final<<<BO*64, tpb, 0, stream>>>(A, ss, out, O);
    }
  };

  so3(X1, X1, X1, 25, g1, bb1, Kh1, 25, b1c, X2, 0);
  k_bnstats<<<dim3(25,64), tpb, 0, stream>>>(X2, 25, part);
  so3(X1, X2, X2, 50, g2, bb2, Kh2, 25, b2c, X3, 0);
  k_bnstats<<<dim3(25,64), tpb, 0, stream>>>(X3, 50, part);
  so3(X1, X2, X3, 75, g3, bb3, Kh3, 36, b3c, nullptr, 1);
}